// Round 1
// baseline (853.509 us; speedup 1.0000x reference)
//
#include <hip/hip_runtime.h>
#include <math.h>

#define NN 50000
#define EE 800000
#define IN_DIM 512
#define HC 128
#define CD 64
// CSR slots = E + N (one self-loop per node)
#define CSR_TOT (EE + NN)

// ---------------------------------------------------------------------------
// GEMM: out[M,256] = A[M,K] @ [w0 | w1] + [b0 | b1]   (w* are [K,128])
// block 256 threads, tile 128x128, grid (ceil(M/128), 2)
// ---------------------------------------------------------------------------
__global__ __launch_bounds__(256) void gemm_dual(
    const float* __restrict__ A, int M, int K,
    const float* __restrict__ w0, const float* __restrict__ b0,
    const float* __restrict__ w1, const float* __restrict__ b1,
    float* __restrict__ out)
{
  const int bm = blockIdx.x, bn = blockIdx.y;
  const float* W    = bn ? w1 : w0;
  const float* bias = bn ? b1 : b0;
  __shared__ float As[32][128];   // [k][m]
  __shared__ float Ws[32][128];   // [k][c]
  const int tid = threadIdx.x;
  const int tr = tid >> 4, tc = tid & 15;   // 16x16 thread grid, 8x8 per thread
  float acc[8][8];
#pragma unroll
  for (int i = 0; i < 8; ++i)
#pragma unroll
    for (int j = 0; j < 8; ++j) acc[i][j] = 0.f;
  const int row0 = bm * 128;

  for (int k0 = 0; k0 < K; k0 += 32) {
    // A chunk -> As[k][m], transposed store
#pragma unroll
    for (int l = 0; l < 4; ++l) {
      int f = tid + l * 256;          // float4 id, 1024 total
      int m = f >> 3;                 // 0..127
      int kp = (f & 7) << 2;          // 0..28
      float4 v = make_float4(0.f, 0.f, 0.f, 0.f);
      int row = row0 + m;
      if (row < M) v = *reinterpret_cast<const float4*>(&A[(size_t)row * K + k0 + kp]);
      As[kp + 0][m] = v.x; As[kp + 1][m] = v.y; As[kp + 2][m] = v.z; As[kp + 3][m] = v.w;
    }
    // W chunk -> Ws[k][c]
#pragma unroll
    for (int l = 0; l < 4; ++l) {
      int f = tid + l * 256;
      int k = f >> 5;                 // 0..31
      int cp = (f & 31) << 2;         // 0..124
      float4 v = *reinterpret_cast<const float4*>(&W[(size_t)(k0 + k) * 128 + cp]);
      *reinterpret_cast<float4*>(&Ws[k][cp]) = v;
    }
    __syncthreads();
#pragma unroll
    for (int kk = 0; kk < 32; ++kk) {
      float a[8], w[8];
      *reinterpret_cast<float4*>(&a[0]) = *reinterpret_cast<const float4*>(&As[kk][tr * 8]);
      *reinterpret_cast<float4*>(&a[4]) = *reinterpret_cast<const float4*>(&As[kk][tr * 8 + 4]);
      *reinterpret_cast<float4*>(&w[0]) = *reinterpret_cast<const float4*>(&Ws[kk][tc * 8]);
      *reinterpret_cast<float4*>(&w[4]) = *reinterpret_cast<const float4*>(&Ws[kk][tc * 8 + 4]);
#pragma unroll
      for (int i = 0; i < 8; ++i)
#pragma unroll
        for (int j = 0; j < 8; ++j)
          acc[i][j] = fmaf(a[i], w[j], acc[i][j]);
    }
    __syncthreads();
  }

#pragma unroll
  for (int i = 0; i < 8; ++i) {
    int row = row0 + tr * 8 + i;
    if (row >= M) continue;
#pragma unroll
    for (int j = 0; j < 8; j += 4) {
      float4 v;
      v.x = acc[i][j + 0] + bias[tc * 8 + j + 0];
      v.y = acc[i][j + 1] + bias[tc * 8 + j + 1];
      v.z = acc[i][j + 2] + bias[tc * 8 + j + 2];
      v.w = acc[i][j + 3] + bias[tc * 8 + j + 3];
      *reinterpret_cast<float4*>(&out[(size_t)row * 256 + bn * 128 + tc * 8 + j]) = v;
    }
  }
}

// ---------------------------------------------------------------------------
// CSR build helpers
// ---------------------------------------------------------------------------
__global__ void count_deg(const int* __restrict__ ei, const float* __restrict__ ea,
                          int* __restrict__ deg, float* __restrict__ sums)
{
  int e = blockIdx.x * 256 + threadIdx.x;
  if (e >= EE) return;
  int d = ei[EE + e];
  atomicAdd(&deg[d], 1);
  atomicAdd(&sums[d * 3 + 0], ea[e * 3 + 0]);
  atomicAdd(&sums[d * 3 + 1], ea[e * 3 + 1]);
  atomicAdd(&sums[d * 3 + 2], ea[e * 3 + 2]);
}

__global__ void mean_kernel(const int* __restrict__ deg, const float* __restrict__ sums,
                            float* __restrict__ mean)
{
  int n = blockIdx.x * 256 + threadIdx.x;
  if (n >= NN) return;
  float c = fmaxf((float)deg[n], 1.f);
  mean[n * 3 + 0] = sums[n * 3 + 0] / c;
  mean[n * 3 + 1] = sums[n * 3 + 1] / c;
  mean[n * 3 + 2] = sums[n * 3 + 2] / c;
}

// single-block inclusive scan of (deg[i]+1) -> row_off[i+1], row_off[0]=0
__global__ __launch_bounds__(1024) void scan_kernel(const int* __restrict__ deg,
                                                    int* __restrict__ row_off)
{
  __shared__ int buf[1024];
  __shared__ int carry;
  int tid = threadIdx.x;
  if (tid == 0) { carry = 0; row_off[0] = 0; }
  __syncthreads();
  for (int base = 0; base < NN; base += 1024) {
    int i = base + tid;
    int v = (i < NN) ? (deg[i] + 1) : 0;
    buf[tid] = v;
    __syncthreads();
    for (int off = 1; off < 1024; off <<= 1) {
      int t = (tid >= off) ? buf[tid - off] : 0;
      __syncthreads();
      buf[tid] += t;
      __syncthreads();
    }
    int c = carry;
    if (i < NN) row_off[i + 1] = c + buf[tid];
    __syncthreads();
    if (tid == 1023) carry = c + buf[1023];
    __syncthreads();
  }
}

__global__ void cursor_init(const int* __restrict__ row_off, int* __restrict__ cursor)
{
  int n = blockIdx.x * 256 + threadIdx.x;
  if (n < NN) cursor[n] = row_off[n];
}

__global__ void scatter_edges(const int* __restrict__ ei, int* __restrict__ cursor,
                              int* __restrict__ csr_src, int* __restrict__ csr_eid)
{
  int e = blockIdx.x * 256 + threadIdx.x;
  if (e >= EE) return;
  int s = ei[e];
  int d = ei[EE + e];
  int pos = atomicAdd(&cursor[d], 1);
  csr_src[pos] = s;
  csr_eid[pos] = e;
}

__global__ void self_loops(int* __restrict__ cursor, int* __restrict__ csr_src,
                           int* __restrict__ csr_eid)
{
  int n = blockIdx.x * 256 + threadIdx.x;
  if (n >= NN) return;
  int pos = atomicAdd(&cursor[n], 1);
  csr_src[pos] = n;
  csr_eid[pos] = -1;
}

// ---------------------------------------------------------------------------
// GATv2 gather: one wave per destination node, online segment-softmax.
// xlr row layout: [ xl(128) | xr(128) ], bias already included.
// lane owns channels {lane (head0), lane+64 (head1)}.
// ---------------------------------------------------------------------------
template <bool FINAL>
__global__ __launch_bounds__(256) void gat_gather(
    const float* __restrict__ xlr, const int* __restrict__ row_off,
    const int* __restrict__ csr_src, const int* __restrict__ csr_eid,
    const float* __restrict__ edge_attr, const float* __restrict__ mean_attr,
    const float* __restrict__ we, const float* __restrict__ att,
    const float* __restrict__ bo, const float* __restrict__ pw,
    float* __restrict__ out)
{
  __shared__ float we_s[3 * 128];
  __shared__ float att_s[128];
  __shared__ float bo_s[64];
  __shared__ float pw_s[64];
  int tid = threadIdx.x;
  for (int i = tid; i < 384; i += 256) we_s[i] = we[i];
  if (tid < 128) att_s[tid] = att[tid];
  if (tid < 64) bo_s[tid] = bo[tid];
  if (tid < 64) pw_s[tid] = FINAL ? pw[tid] : 0.f;
  __syncthreads();

  int wv = tid >> 6, lane = tid & 63;
  int n = blockIdx.x * 4 + wv;
  if (n >= NN) return;

  int ro = row_off[n], re = row_off[n + 1];
  float xr0 = xlr[(size_t)n * 256 + 128 + lane];
  float xr1 = xlr[(size_t)n * 256 + 192 + lane];
  float w00 = we_s[lane],      w01 = we_s[128 + lane], w02 = we_s[256 + lane];
  float w10 = we_s[64 + lane], w11 = we_s[192 + lane], w12 = we_s[320 + lane];
  float at0 = att_s[lane], at1 = att_s[64 + lane];

  float m0 = -INFINITY, m1 = -INFINITY;
  float s0 = 0.f, s1 = 0.f, a0 = 0.f, a1 = 0.f;

  for (int i = ro; i < re; ++i) {
    int sidx = csr_src[i];
    int eid  = csr_eid[i];
    const float* ea = (eid >= 0) ? (edge_attr + (size_t)eid * 3)
                                 : (mean_attr + (size_t)n * 3);
    float e0 = ea[0], e1 = ea[1], e2 = ea[2];
    float xl0 = xlr[(size_t)sidx * 256 + lane];
    float xl1 = xlr[(size_t)sidx * 256 + 64 + lane];
    float t0 = xl0 + xr0 + e0 * w00 + e1 * w01 + e2 * w02;
    float t1 = xl1 + xr1 + e0 * w10 + e1 * w11 + e2 * w12;
    t0 = t0 > 0.f ? t0 : 0.2f * t0;
    t1 = t1 > 0.f ? t1 : 0.2f * t1;
    float v0 = t0 * at0, v1 = t1 * at1;
#pragma unroll
    for (int off = 32; off; off >>= 1) {
      v0 += __shfl_xor(v0, off);
      v1 += __shfl_xor(v1, off);
    }
    // online softmax, head 0
    float nm0 = fmaxf(m0, v0);
    float sc0 = __expf(m0 - nm0);
    float p0  = __expf(v0 - nm0);
    s0 = s0 * sc0 + p0;
    a0 = a0 * sc0 + p0 * xl0;
    m0 = nm0;
    // head 1
    float nm1 = fmaxf(m1, v1);
    float sc1 = __expf(m1 - nm1);
    float p1  = __expf(v1 - nm1);
    s1 = s1 * sc1 + p1;
    a1 = a1 * sc1 + p1 * xl1;
    m1 = nm1;
  }

  float r = 0.5f * (a0 / s0 + a1 / s1) + bo_s[lane];
  if (FINAL) r = (r >= 0.f) ? r : pw_s[lane] * r;
  out[(size_t)n * 64 + lane] = r;
}

// ---------------------------------------------------------------------------
extern "C" void kernel_launch(void* const* d_in, const int* in_sizes, int n_in,
                              void* d_out, int out_size, void* d_ws, size_t ws_size,
                              hipStream_t stream)
{
  const float* x        = (const float*)d_in[0];
  const int*   ei       = (const int*)d_in[1];   // [2,E] int32
  const float* eattr    = (const float*)d_in[2];
  const float* wl1 = (const float*)d_in[3];
  const float* bl1 = (const float*)d_in[4];
  const float* wr1 = (const float*)d_in[5];
  const float* br1 = (const float*)d_in[6];
  const float* we1 = (const float*)d_in[7];
  const float* att1 = (const float*)d_in[8];
  const float* bo1 = (const float*)d_in[9];
  const float* wl2 = (const float*)d_in[10];
  const float* bl2 = (const float*)d_in[11];
  const float* wr2 = (const float*)d_in[12];
  const float* br2 = (const float*)d_in[13];
  const float* we2 = (const float*)d_in[14];
  const float* att2 = (const float*)d_in[15];
  const float* bo2 = (const float*)d_in[16];
  const float* prelu = (const float*)d_in[17];
  float* out = (float*)d_out;

  // workspace layout
  float* fws  = (float*)d_ws;
  float* xlr  = fws;                           // N*256 (reused for both layers)
  float* h1   = xlr + (size_t)NN * 256;        // N*64
  float* sums = h1 + (size_t)NN * 64;          // N*3
  float* mean = sums + (size_t)NN * 3;         // N*3
  int* iws      = (int*)(mean + (size_t)NN * 3);
  int* deg      = iws;                         // N
  int* row_off  = deg + NN;                    // N+1
  int* cursor   = row_off + NN + 1;            // N
  int* csr_src  = cursor + NN;                 // E+N
  int* csr_eid  = csr_src + CSR_TOT;           // E+N

  hipMemsetAsync(deg, 0, (size_t)NN * 4, stream);
  hipMemsetAsync(sums, 0, (size_t)NN * 3 * 4, stream);

  int ebl = (EE + 255) / 256;
  int nbl = (NN + 255) / 256;

  count_deg<<<ebl, 256, 0, stream>>>(ei, eattr, deg, sums);
  mean_kernel<<<nbl, 256, 0, stream>>>(deg, sums, mean);
  scan_kernel<<<1, 1024, 0, stream>>>(deg, row_off);
  cursor_init<<<nbl, 256, 0, stream>>>(row_off, cursor);
  scatter_edges<<<ebl, 256, 0, stream>>>(ei, cursor, csr_src, csr_eid);
  self_loops<<<nbl, 256, 0, stream>>>(cursor, csr_src, csr_eid);

  dim3 ggrid((NN + 127) / 128, 2);
  // layer 1
  gemm_dual<<<ggrid, 256, 0, stream>>>(x, NN, IN_DIM, wl1, bl1, wr1, br1, xlr);
  gat_gather<false><<<(NN + 3) / 4, 256, 0, stream>>>(
      xlr, row_off, csr_src, csr_eid, eattr, mean, we1, att1, bo1, prelu, h1);
  // layer 2
  gemm_dual<<<ggrid, 256, 0, stream>>>(h1, NN, CD, wl2, bl2, wr2, br2, xlr);
  gat_gather<true><<<(NN + 3) / 4, 256, 0, stream>>>(
      xlr, row_off, csr_src, csr_eid, eattr, mean, we2, att2, bo2, prelu, out);
}

// Round 2
// 783.003 us; speedup vs baseline: 1.0900x; 1.0900x over previous
//
#include <hip/hip_runtime.h>
#include <math.h>

#define NN 50000
#define EE 800000
#define CSR_TOT (EE + NN)

typedef __attribute__((ext_vector_type(8))) short bf16x8;
typedef __attribute__((ext_vector_type(4))) float f32x4;

__device__ __forceinline__ short f2bf(float f) {
  unsigned u = __float_as_uint(f);
  unsigned r = (u + 0x7FFFu + ((u >> 16) & 1u)) >> 16;
  return (short)r;
}
__device__ __forceinline__ float bf2f(short h) {
  return __uint_as_float(((unsigned)(unsigned short)h) << 16);
}

// ---------------------------------------------------------------------------
// Wt builder: w [K][128] f32 -> wt [128][3K] bf16 rows = [hi | hi | lo]
// ---------------------------------------------------------------------------
__global__ void build_wt(const float* __restrict__ w, short* __restrict__ wt, int K)
{
  int idx = blockIdx.x * 256 + threadIdx.x;
  if (idx >= 128 * K) return;
  int k = idx % K;
  int c = idx / K;
  float v = w[(size_t)k * 128 + c];
  short hi = f2bf(v);
  short lo = f2bf(v - bf2f(hi));
  size_t base = (size_t)c * 3 * K;
  wt[base + k] = hi;
  wt[base + K + k] = hi;
  wt[base + 2 * K + k] = lo;
}

// ---------------------------------------------------------------------------
// bf16x3 split MFMA GEMM: out[M,256] = A[M,K] @ [W0|W1] + [b0|b1]  (f32-accurate)
// A2 = [hi(A) | lo(A) | hi(A)] along K' = 3K, Wt rows are [hi|hi|lo].
// tile 128x128, BK=64, 256 threads (4 waves, each 64x64), grid (ceil(M/128), 2)
// LDS XOR-swizzle: 16B slot kb ^= (row&7)  -> frag ds_read_b128 conflict-free.
// ---------------------------------------------------------------------------
template <int K, int KS>   // KS = K/64
__global__ __launch_bounds__(256) void gemm_mfma(
    const float* __restrict__ A, int M,
    const short* __restrict__ Wt0, const float* __restrict__ b0,
    const short* __restrict__ Wt1, const float* __restrict__ b1,
    float* __restrict__ out)
{
  const int bn = blockIdx.y;
  const short* __restrict__ Wt = bn ? Wt1 : Wt0;
  const float* __restrict__ bias = bn ? b1 : b0;
  __shared__ __align__(16) short As[128][64];
  __shared__ __align__(16) short Ws[128][64];
  const int tid = threadIdx.x;
  const int m0 = blockIdx.x * 128;
  const int lane = tid & 63;
  const int wv = tid >> 6;
  const int wr = wv >> 1, wc = wv & 1;
  const int rsel = lane & 15, ksel = lane >> 4, sx = lane & 7;

  f32x4 acc[4][4];
#pragma unroll
  for (int i = 0; i < 4; ++i)
#pragma unroll
    for (int j = 0; j < 4; ++j) acc[i][j] = (f32x4)(0.f);

  for (int t = 0; t < 3 * KS; ++t) {
    const int phase = t / KS;              // 0: hi, 1: lo, 2: hi
    const int k0 = (t - phase * KS) * 64;
    // ---- stage A (f32 -> split bf16) ----
#pragma unroll
    for (int i = 0; i < 4; ++i) {
      int f = tid + i * 256;               // 0..1023 slots of 8 elems
      int kb = f & 7, m = f >> 3;
      int row = m0 + m;
      float4 v0 = make_float4(0.f, 0.f, 0.f, 0.f), v1 = v0;
      if (row < M) {
        const float* p = A + (size_t)row * K + k0 + kb * 8;
        v0 = *reinterpret_cast<const float4*>(p);
        v1 = *reinterpret_cast<const float4*>(p + 4);
      }
      float xs[8] = {v0.x, v0.y, v0.z, v0.w, v1.x, v1.y, v1.z, v1.w};
      bf16x8 o;
      if (phase == 1) {
#pragma unroll
        for (int j = 0; j < 8; ++j) {
          short h = f2bf(xs[j]);
          o[j] = f2bf(xs[j] - bf2f(h));
        }
      } else {
#pragma unroll
        for (int j = 0; j < 8; ++j) o[j] = f2bf(xs[j]);
      }
      *reinterpret_cast<bf16x8*>(&As[m][(kb ^ (m & 7)) * 8]) = o;
    }
    // ---- stage W (already bf16, already [c][k'] layout) ----
#pragma unroll
    for (int i = 0; i < 4; ++i) {
      int f = tid + i * 256;
      int kb = f & 7, c = f >> 3;
      bf16x8 v = *reinterpret_cast<const bf16x8*>(
          &Wt[(size_t)c * (3 * K) + t * 64 + kb * 8]);
      *reinterpret_cast<bf16x8*>(&Ws[c][(kb ^ (c & 7)) * 8]) = v;
    }
    __syncthreads();
    // ---- MFMA ----
#pragma unroll
    for (int kk = 0; kk < 2; ++kk) {
      bf16x8 af[4], bfv[4];
#pragma unroll
      for (int mf = 0; mf < 4; ++mf)
        af[mf] = *reinterpret_cast<const bf16x8*>(
            &As[wr * 64 + mf * 16 + rsel][((kk * 4 + ksel) ^ sx) * 8]);
#pragma unroll
      for (int cf = 0; cf < 4; ++cf)
        bfv[cf] = *reinterpret_cast<const bf16x8*>(
            &Ws[wc * 64 + cf * 16 + rsel][((kk * 4 + ksel) ^ sx) * 8]);
#pragma unroll
      for (int mf = 0; mf < 4; ++mf)
#pragma unroll
        for (int cf = 0; cf < 4; ++cf)
          acc[mf][cf] = __builtin_amdgcn_mfma_f32_16x16x32_bf16(
              af[mf], bfv[cf], acc[mf][cf], 0, 0, 0);
    }
    __syncthreads();
  }
  // ---- epilogue ----
#pragma unroll
  for (int mf = 0; mf < 4; ++mf) {
#pragma unroll
    for (int j = 0; j < 4; ++j) {
      int row = m0 + wr * 64 + mf * 16 + ksel * 4 + j;
      if (row >= M) continue;
#pragma unroll
      for (int cf = 0; cf < 4; ++cf) {
        int col = wc * 64 + cf * 16 + rsel;
        out[(size_t)row * 256 + bn * 128 + col] = acc[mf][cf][j] + bias[col];
      }
    }
  }
}

// ---------------------------------------------------------------------------
// CSR build helpers
// ---------------------------------------------------------------------------
__global__ void count_deg(const int* __restrict__ ei, const float* __restrict__ ea,
                          int* __restrict__ deg, float* __restrict__ sums)
{
  int e = blockIdx.x * 256 + threadIdx.x;
  if (e >= EE) return;
  int d = ei[EE + e];
  atomicAdd(&deg[d], 1);
  atomicAdd(&sums[d * 3 + 0], ea[e * 3 + 0]);
  atomicAdd(&sums[d * 3 + 1], ea[e * 3 + 1]);
  atomicAdd(&sums[d * 3 + 2], ea[e * 3 + 2]);
}

__global__ void mean_kernel(const int* __restrict__ deg, const float* __restrict__ sums,
                            float* __restrict__ mean)
{
  int n = blockIdx.x * 256 + threadIdx.x;
  if (n >= NN) return;
  float c = fmaxf((float)deg[n], 1.f);
  mean[n * 3 + 0] = sums[n * 3 + 0] / c;
  mean[n * 3 + 1] = sums[n * 3 + 1] / c;
  mean[n * 3 + 2] = sums[n * 3 + 2] / c;
}

__global__ __launch_bounds__(1024) void scan_kernel(const int* __restrict__ deg,
                                                    int* __restrict__ row_off)
{
  __shared__ int buf[1024];
  __shared__ int carry;
  int tid = threadIdx.x;
  if (tid == 0) { carry = 0; row_off[0] = 0; }
  __syncthreads();
  for (int base = 0; base < NN; base += 1024) {
    int i = base + tid;
    int v = (i < NN) ? (deg[i] + 1) : 0;
    buf[tid] = v;
    __syncthreads();
    for (int off = 1; off < 1024; off <<= 1) {
      int t = (tid >= off) ? buf[tid - off] : 0;
      __syncthreads();
      buf[tid] += t;
      __syncthreads();
    }
    int c = carry;
    if (i < NN) row_off[i + 1] = c + buf[tid];
    __syncthreads();
    if (tid == 1023) carry = c + buf[1023];
    __syncthreads();
  }
}

__global__ void cursor_init(const int* __restrict__ row_off, int* __restrict__ cursor)
{
  int n = blockIdx.x * 256 + threadIdx.x;
  if (n < NN) cursor[n] = row_off[n];
}

__global__ void scatter_edges(const int* __restrict__ ei, int* __restrict__ cursor,
                              int* __restrict__ csr_src, int* __restrict__ csr_eid)
{
  int e = blockIdx.x * 256 + threadIdx.x;
  if (e >= EE) return;
  int s = ei[e];
  int d = ei[EE + e];
  int pos = atomicAdd(&cursor[d], 1);
  csr_src[pos] = s;
  csr_eid[pos] = e;
}

__global__ void self_loops(int* __restrict__ cursor, int* __restrict__ csr_src,
                           int* __restrict__ csr_eid)
{
  int n = blockIdx.x * 256 + threadIdx.x;
  if (n >= NN) return;
  int pos = atomicAdd(&cursor[n], 1);
  csr_src[pos] = n;
  csr_eid[pos] = -1;
}

// ---------------------------------------------------------------------------
// GATv2 gather: one wave per destination node, online segment-softmax.
// ---------------------------------------------------------------------------
template <bool FINAL>
__global__ __launch_bounds__(256) void gat_gather(
    const float* __restrict__ xlr, const int* __restrict__ row_off,
    const int* __restrict__ csr_src, const int* __restrict__ csr_eid,
    const float* __restrict__ edge_attr, const float* __restrict__ mean_attr,
    const float* __restrict__ we, const float* __restrict__ att,
    const float* __restrict__ bo, const float* __restrict__ pw,
    float* __restrict__ out)
{
  __shared__ float we_s[3 * 128];
  __shared__ float att_s[128];
  __shared__ float bo_s[64];
  __shared__ float pw_s[64];
  int tid = threadIdx.x;
  for (int i = tid; i < 384; i += 256) we_s[i] = we[i];
  if (tid < 128) att_s[tid] = att[tid];
  if (tid < 64) bo_s[tid] = bo[tid];
  if (tid < 64) pw_s[tid] = FINAL ? pw[tid] : 0.f;
  __syncthreads();

  int wv = tid >> 6, lane = tid & 63;
  int n = blockIdx.x * 4 + wv;
  if (n >= NN) return;

  int ro = row_off[n], re = row_off[n + 1];
  float xr0 = xlr[(size_t)n * 256 + 128 + lane];
  float xr1 = xlr[(size_t)n * 256 + 192 + lane];
  float w00 = we_s[lane],      w01 = we_s[128 + lane], w02 = we_s[256 + lane];
  float w10 = we_s[64 + lane], w11 = we_s[192 + lane], w12 = we_s[320 + lane];
  float at0 = att_s[lane], at1 = att_s[64 + lane];

  float m0 = -INFINITY, m1 = -INFINITY;
  float s0 = 0.f, s1 = 0.f, a0 = 0.f, a1 = 0.f;

  for (int i = ro; i < re; ++i) {
    int sidx = csr_src[i];
    int eid  = csr_eid[i];
    const float* ea = (eid >= 0) ? (edge_attr + (size_t)eid * 3)
                                 : (mean_attr + (size_t)n * 3);
    float e0 = ea[0], e1 = ea[1], e2 = ea[2];
    float xl0 = xlr[(size_t)sidx * 256 + lane];
    float xl1 = xlr[(size_t)sidx * 256 + 64 + lane];
    float t0 = xl0 + xr0 + e0 * w00 + e1 * w01 + e2 * w02;
    float t1 = xl1 + xr1 + e0 * w10 + e1 * w11 + e2 * w12;
    t0 = t0 > 0.f ? t0 : 0.2f * t0;
    t1 = t1 > 0.f ? t1 : 0.2f * t1;
    float v0 = t0 * at0, v1 = t1 * at1;
#pragma unroll
    for (int off = 32; off; off >>= 1) {
      v0 += __shfl_xor(v0, off);
      v1 += __shfl_xor(v1, off);
    }
    float nm0 = fmaxf(m0, v0);
    float sc0 = __expf(m0 - nm0);
    float p0  = __expf(v0 - nm0);
    s0 = s0 * sc0 + p0;
    a0 = a0 * sc0 + p0 * xl0;
    m0 = nm0;
    float nm1 = fmaxf(m1, v1);
    float sc1 = __expf(m1 - nm1);
    float p1  = __expf(v1 - nm1);
    s1 = s1 * sc1 + p1;
    a1 = a1 * sc1 + p1 * xl1;
    m1 = nm1;
  }

  float r = 0.5f * (a0 / s0 + a1 / s1) + bo_s[lane];
  if (FINAL) r = (r >= 0.f) ? r : pw_s[lane] * r;
  out[(size_t)n * 64 + lane] = r;
}

// ---------------------------------------------------------------------------
extern "C" void kernel_launch(void* const* d_in, const int* in_sizes, int n_in,
                              void* d_out, int out_size, void* d_ws, size_t ws_size,
                              hipStream_t stream)
{
  const float* x     = (const float*)d_in[0];
  const int*   ei    = (const int*)d_in[1];
  const float* eattr = (const float*)d_in[2];
  const float* wl1 = (const float*)d_in[3];
  const float* bl1 = (const float*)d_in[4];
  const float* wr1 = (const float*)d_in[5];
  const float* br1 = (const float*)d_in[6];
  const float* we1 = (const float*)d_in[7];
  const float* att1 = (const float*)d_in[8];
  const float* bo1 = (const float*)d_in[9];
  const float* wl2 = (const float*)d_in[10];
  const float* bl2 = (const float*)d_in[11];
  const float* wr2 = (const float*)d_in[12];
  const float* br2 = (const float*)d_in[13];
  const float* we2 = (const float*)d_in[14];
  const float* att2 = (const float*)d_in[15];
  const float* bo2 = (const float*)d_in[16];
  const float* prelu = (const float*)d_in[17];
  float* out = (float*)d_out;

  // workspace layout
  float* fws  = (float*)d_ws;
  float* xlr  = fws;                           // N*256
  float* h1   = xlr + (size_t)NN * 256;        // N*64
  float* sums = h1 + (size_t)NN * 64;          // N*3
  float* mean = sums + (size_t)NN * 3;         // N*3
  int* iws      = (int*)(mean + (size_t)NN * 3);
  int* deg      = iws;
  int* row_off  = deg + NN;
  int* cursor   = row_off + NN + 1;
  int* csr_src  = cursor + NN;
  int* csr_eid  = csr_src + CSR_TOT;

  // Wt buffers alias dead regions:
  //  wt1 (2 x 128x1536 bf16 = 786KB) lives in h1 (12.8MB) -- h1 written only
  //  AFTER gemm1 consumed wt1.
  //  wt2 (2 x 128x192 bf16 = 98KB) lives in sums (600KB) -- sums dead after
  //  mean_kernel.
  short* wt1a = (short*)h1;
  short* wt1b = wt1a + (size_t)128 * 1536;
  short* wt2a = (short*)sums;
  short* wt2b = wt2a + (size_t)128 * 192;

  hipMemsetAsync(deg, 0, (size_t)NN * 4, stream);
  hipMemsetAsync(sums, 0, (size_t)NN * 3 * 4, stream);

  int ebl = (EE + 255) / 256;
  int nbl = (NN + 255) / 256;

  count_deg<<<ebl, 256, 0, stream>>>(ei, eattr, deg, sums);
  mean_kernel<<<nbl, 256, 0, stream>>>(deg, sums, mean);
  scan_kernel<<<1, 1024, 0, stream>>>(deg, row_off);
  cursor_init<<<nbl, 256, 0, stream>>>(row_off, cursor);
  scatter_edges<<<ebl, 256, 0, stream>>>(ei, cursor, csr_src, csr_eid);
  self_loops<<<nbl, 256, 0, stream>>>(cursor, csr_src, csr_eid);

  dim3 ggrid((NN + 127) / 128, 2);

  // layer 1
  build_wt<<<(128 * 512 + 255) / 256, 256, 0, stream>>>(wl1, wt1a, 512);
  build_wt<<<(128 * 512 + 255) / 256, 256, 0, stream>>>(wr1, wt1b, 512);
  gemm_mfma<512, 8><<<ggrid, 256, 0, stream>>>(x, NN, wt1a, bl1, wt1b, br1, xlr);
  gat_gather<false><<<(NN + 3) / 4, 256, 0, stream>>>(
      xlr, row_off, csr_src, csr_eid, eattr, mean, we1, att1, bo1, prelu, h1);

  // layer 2
  build_wt<<<(128 * 64 + 255) / 256, 256, 0, stream>>>(wl2, wt2a, 64);
  build_wt<<<(128 * 64 + 255) / 256, 256, 0, stream>>>(wr2, wt2b, 64);
  gemm_mfma<64, 1><<<ggrid, 256, 0, stream>>>(h1, NN, wt2a, bl2, wt2b, br2, xlr);
  gat_gather<true><<<(NN + 3) / 4, 256, 0, stream>>>(
      xlr, row_off, csr_src, csr_eid, eattr, mean, we2, att2, bo2, prelu, out);
}

// Round 3
// 606.977 us; speedup vs baseline: 1.4062x; 1.2900x over previous
//
#include <hip/hip_runtime.h>
#include <math.h>

#define NN 50000
#define EE 800000
#define CSR_TOT (EE + NN)
#define NB ((NN + 255) / 256)   // 196 scan blocks

typedef __attribute__((ext_vector_type(8))) short bf16x8;
typedef __attribute__((ext_vector_type(4))) float f32x4;

__device__ __forceinline__ short f2bf(float f) {
  unsigned u = __float_as_uint(f);
  unsigned r = (u + 0x7FFFu + ((u >> 16) & 1u)) >> 16;
  return (short)r;
}
__device__ __forceinline__ float bf2f(short h) {
  return __uint_as_float(((unsigned)(unsigned short)h) << 16);
}

// ---------------------------------------------------------------------------
// Wt builder: w [K][128] f32 -> wt [128][3K] bf16 rows = [hi | hi | lo]
// ---------------------------------------------------------------------------
__global__ void build_wt(const float* __restrict__ w, short* __restrict__ wt, int K)
{
  int idx = blockIdx.x * 256 + threadIdx.x;
  if (idx >= 128 * K) return;
  int k = idx % K;
  int c = idx / K;
  float v = w[(size_t)k * 128 + c];
  short hi = f2bf(v);
  short lo = f2bf(v - bf2f(hi));
  size_t base = (size_t)c * 3 * K;
  wt[base + k] = hi;
  wt[base + K + k] = hi;
  wt[base + 2 * K + k] = lo;
}

// ---------------------------------------------------------------------------
// bf16x3 split MFMA GEMM (unchanged from round 2)
// ---------------------------------------------------------------------------
template <int K, int KS>
__global__ __launch_bounds__(256) void gemm_mfma(
    const float* __restrict__ A, int M,
    const short* __restrict__ Wt0, const float* __restrict__ b0,
    const short* __restrict__ Wt1, const float* __restrict__ b1,
    float* __restrict__ out)
{
  const int bn = blockIdx.y;
  const short* __restrict__ Wt = bn ? Wt1 : Wt0;
  const float* __restrict__ bias = bn ? b1 : b0;
  __shared__ __align__(16) short As[128][64];
  __shared__ __align__(16) short Ws[128][64];
  const int tid = threadIdx.x;
  const int m0 = blockIdx.x * 128;
  const int lane = tid & 63;
  const int wv = tid >> 6;
  const int wr = wv >> 1, wc = wv & 1;
  const int rsel = lane & 15, ksel = lane >> 4, sx = lane & 7;

  f32x4 acc[4][4];
#pragma unroll
  for (int i = 0; i < 4; ++i)
#pragma unroll
    for (int j = 0; j < 4; ++j) acc[i][j] = (f32x4)(0.f);

  for (int t = 0; t < 3 * KS; ++t) {
    const int phase = t / KS;
    const int k0 = (t - phase * KS) * 64;
#pragma unroll
    for (int i = 0; i < 4; ++i) {
      int f = tid + i * 256;
      int kb = f & 7, m = f >> 3;
      int row = m0 + m;
      float4 v0 = make_float4(0.f, 0.f, 0.f, 0.f), v1 = v0;
      if (row < M) {
        const float* p = A + (size_t)row * K + k0 + kb * 8;
        v0 = *reinterpret_cast<const float4*>(p);
        v1 = *reinterpret_cast<const float4*>(p + 4);
      }
      float xs[8] = {v0.x, v0.y, v0.z, v0.w, v1.x, v1.y, v1.z, v1.w};
      bf16x8 o;
      if (phase == 1) {
#pragma unroll
        for (int j = 0; j < 8; ++j) {
          short h = f2bf(xs[j]);
          o[j] = f2bf(xs[j] - bf2f(h));
        }
      } else {
#pragma unroll
        for (int j = 0; j < 8; ++j) o[j] = f2bf(xs[j]);
      }
      *reinterpret_cast<bf16x8*>(&As[m][(kb ^ (m & 7)) * 8]) = o;
    }
#pragma unroll
    for (int i = 0; i < 4; ++i) {
      int f = tid + i * 256;
      int kb = f & 7, c = f >> 3;
      bf16x8 v = *reinterpret_cast<const bf16x8*>(
          &Wt[(size_t)c * (3 * K) + t * 64 + kb * 8]);
      *reinterpret_cast<bf16x8*>(&Ws[c][(kb ^ (c & 7)) * 8]) = v;
    }
    __syncthreads();
#pragma unroll
    for (int kk = 0; kk < 2; ++kk) {
      bf16x8 af[4], bfv[4];
#pragma unroll
      for (int mf = 0; mf < 4; ++mf)
        af[mf] = *reinterpret_cast<const bf16x8*>(
            &As[wr * 64 + mf * 16 + rsel][((kk * 4 + ksel) ^ sx) * 8]);
#pragma unroll
      for (int cf = 0; cf < 4; ++cf)
        bfv[cf] = *reinterpret_cast<const bf16x8*>(
            &Ws[wc * 64 + cf * 16 + rsel][((kk * 4 + ksel) ^ sx) * 8]);
#pragma unroll
      for (int mf = 0; mf < 4; ++mf)
#pragma unroll
        for (int cf = 0; cf < 4; ++cf)
          acc[mf][cf] = __builtin_amdgcn_mfma_f32_16x16x32_bf16(
              af[mf], bfv[cf], acc[mf][cf], 0, 0, 0);
    }
    __syncthreads();
  }
#pragma unroll
  for (int mf = 0; mf < 4; ++mf) {
#pragma unroll
    for (int j = 0; j < 4; ++j) {
      int row = m0 + wr * 64 + mf * 16 + ksel * 4 + j;
      if (row >= M) continue;
#pragma unroll
      for (int cf = 0; cf < 4; ++cf) {
        int col = wc * 64 + cf * 16 + rsel;
        out[(size_t)row * 256 + bn * 128 + col] = acc[mf][cf][j] + bias[col];
      }
    }
  }
}

// ---------------------------------------------------------------------------
// CSR build
// ---------------------------------------------------------------------------
__global__ void count_deg(const int* __restrict__ ei, const float* __restrict__ ea,
                          int* __restrict__ deg, float* __restrict__ sums)
{
  int e = blockIdx.x * 256 + threadIdx.x;
  if (e >= EE) return;
  int d = ei[EE + e];
  atomicAdd(&deg[d], 1);
  atomicAdd(&sums[d * 3 + 0], ea[e * 3 + 0]);
  atomicAdd(&sums[d * 3 + 1], ea[e * 3 + 1]);
  atomicAdd(&sums[d * 3 + 2], ea[e * 3 + 2]);
}

__global__ void mean_kernel(const int* __restrict__ deg, const float* __restrict__ sums,
                            float* __restrict__ mean)
{
  int n = blockIdx.x * 256 + threadIdx.x;
  if (n >= NN) return;
  float c = fmaxf((float)deg[n], 1.f);
  mean[n * 3 + 0] = sums[n * 3 + 0] / c;
  mean[n * 3 + 1] = sums[n * 3 + 1] / c;
  mean[n * 3 + 2] = sums[n * 3 + 2] / c;
}

// hierarchical scan of (deg[i]+1): scan_blocks -> scan_tops -> scan_add
__global__ __launch_bounds__(256) void scan_blocks(const int* __restrict__ deg,
                                                   int* __restrict__ row_off,
                                                   int* __restrict__ bsum)
{
  int b = blockIdx.x, tid = threadIdx.x;
  int i = b * 256 + tid;
  int v = (i < NN) ? deg[i] + 1 : 0;
  int lane = tid & 63, wv = tid >> 6;
  int x = v;
#pragma unroll
  for (int off = 1; off < 64; off <<= 1) {
    int t = __shfl_up(x, off);
    if (lane >= off) x += t;
  }
  __shared__ int ws[4], wo[4];
  if (lane == 63) ws[wv] = x;
  __syncthreads();
  if (tid == 0) {
    int s = 0;
#pragma unroll
    for (int k = 0; k < 4; ++k) { wo[k] = s; s += ws[k]; }
    bsum[b] = s;
  }
  __syncthreads();
  x += wo[wv];
  if (i < NN) row_off[i + 1] = x;
}

__global__ __launch_bounds__(256) void scan_tops(const int* __restrict__ bsum,
                                                 int* __restrict__ boff)
{
  int tid = threadIdx.x;
  int v = (tid < NB) ? bsum[tid] : 0;
  int lane = tid & 63, wv = tid >> 6;
  int x = v;
#pragma unroll
  for (int off = 1; off < 64; off <<= 1) {
    int t = __shfl_up(x, off);
    if (lane >= off) x += t;
  }
  __shared__ int ws[4], wo[4];
  if (lane == 63) ws[wv] = x;
  __syncthreads();
  if (tid == 0) {
    int s = 0;
#pragma unroll
    for (int k = 0; k < 4; ++k) { wo[k] = s; s += ws[k]; }
  }
  __syncthreads();
  x += wo[wv];
  if (tid < NB) boff[tid] = x - v;   // exclusive
}

__global__ void scan_add(int* __restrict__ row_off, const int* __restrict__ boff)
{
  int i = blockIdx.x * 256 + threadIdx.x;
  if (i == 0) row_off[0] = 0;
  if (i < NN) row_off[i + 1] += boff[blockIdx.x];
}

__global__ void cursor_init(const int* __restrict__ row_off, int* __restrict__ cursor)
{
  int n = blockIdx.x * 256 + threadIdx.x;
  if (n < NN) cursor[n] = row_off[n];
}

__global__ void scatter_edges(const int* __restrict__ ei, int* __restrict__ cursor,
                              int2* __restrict__ csr)
{
  int e = blockIdx.x * 256 + threadIdx.x;
  if (e >= EE) return;
  int s = ei[e];
  int d = ei[EE + e];
  int pos = atomicAdd(&cursor[d], 1);
  csr[pos] = make_int2(s, e);
}

__global__ void self_loops(int* __restrict__ cursor, int2* __restrict__ csr)
{
  int n = blockIdx.x * 256 + threadIdx.x;
  if (n >= NN) return;
  int pos = atomicAdd(&cursor[n], 1);
  csr[pos] = make_int2(n, -1);
}

// ---------------------------------------------------------------------------
// GATv2 gather: wave per dst node. Lanes 0-31 = head0, lanes 32-63 = head1,
// each lane owns a float2 channel pair. 5-shfl score reduce per edge (both
// heads at once), 2-edge unrolled online softmax.
// ---------------------------------------------------------------------------
template <bool FINAL>
__global__ __launch_bounds__(256) void gat_gather(
    const float* __restrict__ xlr, const int* __restrict__ row_off,
    const int2* __restrict__ csr,
    const float* __restrict__ edge_attr, const float* __restrict__ mean_attr,
    const float* __restrict__ we, const float* __restrict__ att,
    const float* __restrict__ bo, const float* __restrict__ pw,
    float* __restrict__ out)
{
  __shared__ float we_s[384];
  __shared__ float att_s[128];
  __shared__ float bo_s[64], pw_s[64];
  int tid = threadIdx.x;
  for (int i = tid; i < 384; i += 256) we_s[i] = we[i];
  if (tid < 128) att_s[tid] = att[tid];
  if (tid < 64) { bo_s[tid] = bo[tid]; pw_s[tid] = FINAL ? pw[tid] : 0.f; }
  __syncthreads();

  int wv = tid >> 6, lane = tid & 63;
  int n = blockIdx.x * 4 + wv;
  if (n >= NN) return;

  const int half = lane >> 5;           // head id
  const int hl = lane & 31;
  const int cb = half * 64 + hl * 2;    // channel-pair base in [0,128)

  float2 xr = *reinterpret_cast<const float2*>(&xlr[(size_t)n * 256 + 128 + cb]);
  float w0a = we_s[cb],       w0b = we_s[cb + 1];
  float w1a = we_s[128 + cb], w1b = we_s[128 + cb + 1];
  float w2a = we_s[256 + cb], w2b = we_s[256 + cb + 1];
  float ata = att_s[cb], atb = att_s[cb + 1];

  int ro = row_off[n], re = row_off[n + 1];
  float m = -INFINITY, s = 0.f, a0 = 0.f, a1 = 0.f;

  int i = ro;
  for (; i + 1 < re; i += 2) {
    int2 cA = csr[i];
    int2 cB = csr[i + 1];
    const float* pA = (cA.y >= 0) ? edge_attr + (size_t)cA.y * 3
                                  : mean_attr + (size_t)n * 3;
    const float* pB = (cB.y >= 0) ? edge_attr + (size_t)cB.y * 3
                                  : mean_attr + (size_t)n * 3;
    float2 xlA = *reinterpret_cast<const float2*>(&xlr[(size_t)cA.x * 256 + cb]);
    float2 xlB = *reinterpret_cast<const float2*>(&xlr[(size_t)cB.x * 256 + cb]);
    float eA0 = pA[0], eA1 = pA[1], eA2 = pA[2];
    float eB0 = pB[0], eB1 = pB[1], eB2 = pB[2];
    float tA0 = xlA.x + xr.x + eA0 * w0a + eA1 * w1a + eA2 * w2a;
    float tA1 = xlA.y + xr.y + eA0 * w0b + eA1 * w1b + eA2 * w2b;
    float tB0 = xlB.x + xr.x + eB0 * w0a + eB1 * w1a + eB2 * w2a;
    float tB1 = xlB.y + xr.y + eB0 * w0b + eB1 * w1b + eB2 * w2b;
    tA0 = tA0 > 0.f ? tA0 : 0.2f * tA0;
    tA1 = tA1 > 0.f ? tA1 : 0.2f * tA1;
    tB0 = tB0 > 0.f ? tB0 : 0.2f * tB0;
    tB1 = tB1 > 0.f ? tB1 : 0.2f * tB1;
    float vA = tA0 * ata + tA1 * atb;
    float vB = tB0 * ata + tB1 * atb;
#pragma unroll
    for (int off = 16; off; off >>= 1) {
      vA += __shfl_xor(vA, off);
      vB += __shfl_xor(vB, off);
    }
    float nm = fmaxf(m, fmaxf(vA, vB));
    float sc = __expf(m - nm);
    float qA = __expf(vA - nm);
    float qB = __expf(vB - nm);
    s = s * sc + qA + qB;
    a0 = a0 * sc + qA * xlA.x + qB * xlB.x;
    a1 = a1 * sc + qA * xlA.y + qB * xlB.y;
    m = nm;
  }
  if (i < re) {
    int2 cA = csr[i];
    const float* pA = (cA.y >= 0) ? edge_attr + (size_t)cA.y * 3
                                  : mean_attr + (size_t)n * 3;
    float2 xlA = *reinterpret_cast<const float2*>(&xlr[(size_t)cA.x * 256 + cb]);
    float eA0 = pA[0], eA1 = pA[1], eA2 = pA[2];
    float tA0 = xlA.x + xr.x + eA0 * w0a + eA1 * w1a + eA2 * w2a;
    float tA1 = xlA.y + xr.y + eA0 * w0b + eA1 * w1b + eA2 * w2b;
    tA0 = tA0 > 0.f ? tA0 : 0.2f * tA0;
    tA1 = tA1 > 0.f ? tA1 : 0.2f * tA1;
    float vA = tA0 * ata + tA1 * atb;
#pragma unroll
    for (int off = 16; off; off >>= 1) vA += __shfl_xor(vA, off);
    float nm = fmaxf(m, vA);
    float sc = __expf(m - nm);
    float qA = __expf(vA - nm);
    s = s * sc + qA;
    a0 = a0 * sc + qA * xlA.x;
    a1 = a1 * sc + qA * xlA.y;
    m = nm;
  }

  float f0 = a0 / s, f1 = a1 / s;
  float g0 = __shfl_xor(f0, 32);
  float g1 = __shfl_xor(f1, 32);
  if (half == 0) {
    float2 r;
    r.x = 0.5f * (f0 + g0) + bo_s[hl * 2];
    r.y = 0.5f * (f1 + g1) + bo_s[hl * 2 + 1];
    if (FINAL) {
      r.x = (r.x >= 0.f) ? r.x : pw_s[hl * 2] * r.x;
      r.y = (r.y >= 0.f) ? r.y : pw_s[hl * 2 + 1] * r.y;
    }
    *reinterpret_cast<float2*>(&out[(size_t)n * 64 + hl * 2]) = r;
  }
}

// ---------------------------------------------------------------------------
extern "C" void kernel_launch(void* const* d_in, const int* in_sizes, int n_in,
                              void* d_out, int out_size, void* d_ws, size_t ws_size,
                              hipStream_t stream)
{
  const float* x     = (const float*)d_in[0];
  const int*   ei    = (const int*)d_in[1];
  const float* eattr = (const float*)d_in[2];
  const float* wl1 = (const float*)d_in[3];
  const float* bl1 = (const float*)d_in[4];
  const float* wr1 = (const float*)d_in[5];
  const float* br1 = (const float*)d_in[6];
  const float* we1 = (const float*)d_in[7];
  const float* att1 = (const float*)d_in[8];
  const float* bo1 = (const float*)d_in[9];
  const float* wl2 = (const float*)d_in[10];
  const float* bl2 = (const float*)d_in[11];
  const float* wr2 = (const float*)d_in[12];
  const float* br2 = (const float*)d_in[13];
  const float* we2 = (const float*)d_in[14];
  const float* att2 = (const float*)d_in[15];
  const float* bo2 = (const float*)d_in[16];
  const float* prelu = (const float*)d_in[17];
  float* out = (float*)d_out;

  float* fws  = (float*)d_ws;
  float* xlr  = fws;                           // N*256
  float* h1   = xlr + (size_t)NN * 256;        // N*64
  float* sums = h1 + (size_t)NN * 64;          // N*3
  float* mean = sums + (size_t)NN * 3;         // N*3
  int* iws      = (int*)(mean + (size_t)NN * 3);
  int* deg      = iws;                         // N
  int* row_off  = deg + NN;                    // N+1
  int* cursor   = row_off + NN + 1;            // N
  int2* csr     = (int2*)(cursor + NN);        // CSR_TOT int2
  int* bsum     = (int*)(csr + CSR_TOT);       // NB
  int* boff     = bsum + NB;                   // NB

  short* wt1a = (short*)h1;                    // dead until gat1 writes h1
  short* wt1b = wt1a + (size_t)128 * 1536;
  short* wt2a = (short*)sums;                  // dead after mean_kernel
  short* wt2b = wt2a + (size_t)128 * 192;

  hipMemsetAsync(deg, 0, (size_t)NN * 4, stream);
  hipMemsetAsync(sums, 0, (size_t)NN * 3 * 4, stream);

  int ebl = (EE + 255) / 256;
  int nbl = (NN + 255) / 256;

  count_deg<<<ebl, 256, 0, stream>>>(ei, eattr, deg, sums);
  mean_kernel<<<nbl, 256, 0, stream>>>(deg, sums, mean);
  scan_blocks<<<NB, 256, 0, stream>>>(deg, row_off, bsum);
  scan_tops<<<1, 256, 0, stream>>>(bsum, boff);
  scan_add<<<NB, 256, 0, stream>>>(row_off, boff);
  cursor_init<<<nbl, 256, 0, stream>>>(row_off, cursor);
  scatter_edges<<<ebl, 256, 0, stream>>>(ei, cursor, csr);
  self_loops<<<nbl, 256, 0, stream>>>(cursor, csr);

  dim3 ggrid((NN + 127) / 128, 2);

  // layer 1
  build_wt<<<(128 * 512 + 255) / 256, 256, 0, stream>>>(wl1, wt1a, 512);
  build_wt<<<(128 * 512 + 255) / 256, 256, 0, stream>>>(wr1, wt1b, 512);
  gemm_mfma<512, 8><<<ggrid, 256, 0, stream>>>(x, NN, wt1a, bl1, wt1b, br1, xlr);
  gat_gather<false><<<(NN + 3) / 4, 256, 0, stream>>>(
      xlr, row_off, csr, eattr, mean, we1, att1, bo1, prelu, h1);

  // layer 2
  build_wt<<<(128 * 64 + 255) / 256, 256, 0, stream>>>(wl2, wt2a, 64);
  build_wt<<<(128 * 64 + 255) / 256, 256, 0, stream>>>(wr2, wt2b, 64);
  gemm_mfma<64, 1><<<ggrid, 256, 0, stream>>>(h1, NN, wt2a, bl2, wt2b, br2, xlr);
  gat_gather<true><<<(NN + 3) / 4, 256, 0, stream>>>(
      xlr, row_off, csr, eattr, mean, we2, att2, bo2, prelu, out);
}

// Round 4
// 456.172 us; speedup vs baseline: 1.8710x; 1.3306x over previous
//
#include <hip/hip_runtime.h>
#include <math.h>

#define NN 50000
#define EE 800000
#define NB ((NN + 255) / 256)   // 196 scan blocks

typedef __attribute__((ext_vector_type(8))) short bf16x8;
typedef __attribute__((ext_vector_type(4))) float f32x4;

__device__ __forceinline__ short f2bf(float f) {
  unsigned u = __float_as_uint(f);
  unsigned r = (u + 0x7FFFu + ((u >> 16) & 1u)) >> 16;
  return (short)r;
}
__device__ __forceinline__ float bf2f(short h) {
  return __uint_as_float(((unsigned)(unsigned short)h) << 16);
}

// ---------------------------------------------------------------------------
// Wt builder: w [K][128] f32 -> wt [128][3K] bf16 rows = [hi | hi | lo]
// ---------------------------------------------------------------------------
__global__ void build_wt(const float* __restrict__ w, short* __restrict__ wt, int K)
{
  int idx = blockIdx.x * 256 + threadIdx.x;
  if (idx >= 128 * K) return;
  int k = idx % K;
  int c = idx / K;
  float v = w[(size_t)k * 128 + c];
  short hi = f2bf(v);
  short lo = f2bf(v - bf2f(hi));
  size_t base = (size_t)c * 3 * K;
  wt[base + k] = hi;
  wt[base + K + k] = hi;
  wt[base + 2 * K + k] = lo;
}

// ---------------------------------------------------------------------------
// bf16x3 split MFMA GEMM: out[M,256] = A[M,K] @ [W0|W1] + [b0|b1]
// ---------------------------------------------------------------------------
template <int K, int KS>
__global__ __launch_bounds__(256) void gemm_mfma(
    const float* __restrict__ A, int M,
    const short* __restrict__ Wt0, const float* __restrict__ b0,
    const short* __restrict__ Wt1, const float* __restrict__ b1,
    float* __restrict__ out)
{
  const int bn = blockIdx.y;
  const short* __restrict__ Wt = bn ? Wt1 : Wt0;
  const float* __restrict__ bias = bn ? b1 : b0;
  __shared__ __align__(16) short As[128][64];
  __shared__ __align__(16) short Ws[128][64];
  const int tid = threadIdx.x;
  const int m0 = blockIdx.x * 128;
  const int lane = tid & 63;
  const int wv = tid >> 6;
  const int wr = wv >> 1, wc = wv & 1;
  const int rsel = lane & 15, ksel = lane >> 4, sx = lane & 7;

  f32x4 acc[4][4];
#pragma unroll
  for (int i = 0; i < 4; ++i)
#pragma unroll
    for (int j = 0; j < 4; ++j) acc[i][j] = (f32x4)(0.f);

  for (int t = 0; t < 3 * KS; ++t) {
    const int phase = t / KS;
    const int k0 = (t - phase * KS) * 64;
#pragma unroll
    for (int i = 0; i < 4; ++i) {
      int f = tid + i * 256;
      int kb = f & 7, m = f >> 3;
      int row = m0 + m;
      float4 v0 = make_float4(0.f, 0.f, 0.f, 0.f), v1 = v0;
      if (row < M) {
        const float* p = A + (size_t)row * K + k0 + kb * 8;
        v0 = *reinterpret_cast<const float4*>(p);
        v1 = *reinterpret_cast<const float4*>(p + 4);
      }
      float xs[8] = {v0.x, v0.y, v0.z, v0.w, v1.x, v1.y, v1.z, v1.w};
      bf16x8 o;
      if (phase == 1) {
#pragma unroll
        for (int j = 0; j < 8; ++j) {
          short h = f2bf(xs[j]);
          o[j] = f2bf(xs[j] - bf2f(h));
        }
      } else {
#pragma unroll
        for (int j = 0; j < 8; ++j) o[j] = f2bf(xs[j]);
      }
      *reinterpret_cast<bf16x8*>(&As[m][(kb ^ (m & 7)) * 8]) = o;
    }
#pragma unroll
    for (int i = 0; i < 4; ++i) {
      int f = tid + i * 256;
      int kb = f & 7, c = f >> 3;
      bf16x8 v = *reinterpret_cast<const bf16x8*>(
          &Wt[(size_t)c * (3 * K) + t * 64 + kb * 8]);
      *reinterpret_cast<bf16x8*>(&Ws[c][(kb ^ (c & 7)) * 8]) = v;
    }
    __syncthreads();
#pragma unroll
    for (int kk = 0; kk < 2; ++kk) {
      bf16x8 af[4], bfv[4];
#pragma unroll
      for (int mf = 0; mf < 4; ++mf)
        af[mf] = *reinterpret_cast<const bf16x8*>(
            &As[wr * 64 + mf * 16 + rsel][((kk * 4 + ksel) ^ sx) * 8]);
#pragma unroll
      for (int cf = 0; cf < 4; ++cf)
        bfv[cf] = *reinterpret_cast<const bf16x8*>(
            &Ws[wc * 64 + cf * 16 + rsel][((kk * 4 + ksel) ^ sx) * 8]);
#pragma unroll
      for (int mf = 0; mf < 4; ++mf)
#pragma unroll
        for (int cf = 0; cf < 4; ++cf)
          acc[mf][cf] = __builtin_amdgcn_mfma_f32_16x16x32_bf16(
              af[mf], bfv[cf], acc[mf][cf], 0, 0, 0);
    }
    __syncthreads();
  }
#pragma unroll
  for (int mf = 0; mf < 4; ++mf) {
#pragma unroll
    for (int j = 0; j < 4; ++j) {
      int row = m0 + wr * 64 + mf * 16 + ksel * 4 + j;
      if (row >= M) continue;
#pragma unroll
      for (int cf = 0; cf < 4; ++cf) {
        int col = wc * 64 + cf * 16 + rsel;
        out[(size_t)row * 256 + bn * 128 + col] = acc[mf][cf][j] + bias[col];
      }
    }
  }
}

// ---------------------------------------------------------------------------
// CSR build: int histogram -> scan -> scatter (entry = {src, e0,e1,e2})
// ---------------------------------------------------------------------------
__global__ void count_deg(const int* __restrict__ ei, int* __restrict__ deg)
{
  int e = blockIdx.x * 256 + threadIdx.x;
  if (e >= EE) return;
  atomicAdd(&deg[ei[EE + e]], 1);
}

__global__ __launch_bounds__(256) void scan_blocks(const int* __restrict__ deg,
                                                   int* __restrict__ row_off,
                                                   int* __restrict__ bsum)
{
  int b = blockIdx.x, tid = threadIdx.x;
  int i = b * 256 + tid;
  int v = (i < NN) ? deg[i] : 0;
  int lane = tid & 63, wv = tid >> 6;
  int x = v;
#pragma unroll
  for (int off = 1; off < 64; off <<= 1) {
    int t = __shfl_up(x, off);
    if (lane >= off) x += t;
  }
  __shared__ int ws[4], wo[4];
  if (lane == 63) ws[wv] = x;
  __syncthreads();
  if (tid == 0) {
    int s = 0;
#pragma unroll
    for (int k = 0; k < 4; ++k) { wo[k] = s; s += ws[k]; }
    bsum[b] = s;
  }
  __syncthreads();
  x += wo[wv];
  if (i < NN) row_off[i + 1] = x;
}

__global__ __launch_bounds__(256) void scan_tops(const int* __restrict__ bsum,
                                                 int* __restrict__ boff)
{
  int tid = threadIdx.x;
  int v = (tid < NB) ? bsum[tid] : 0;
  int lane = tid & 63, wv = tid >> 6;
  int x = v;
#pragma unroll
  for (int off = 1; off < 64; off <<= 1) {
    int t = __shfl_up(x, off);
    if (lane >= off) x += t;
  }
  __shared__ int ws[4], wo[4];
  if (lane == 63) ws[wv] = x;
  __syncthreads();
  if (tid == 0) {
    int s = 0;
#pragma unroll
    for (int k = 0; k < 4; ++k) { wo[k] = s; s += ws[k]; }
  }
  __syncthreads();
  x += wo[wv];
  if (tid < NB) boff[tid] = x - v;   // exclusive
}

// finalize row_off, emit cursor (exclusive start per node)
__global__ void scan_add(int* __restrict__ row_off, const int* __restrict__ boff,
                         const int* __restrict__ deg, int* __restrict__ cursor)
{
  int i = blockIdx.x * 256 + threadIdx.x;
  if (i == 0) row_off[0] = 0;
  if (i < NN) {
    int v = row_off[i + 1] + boff[blockIdx.x];
    row_off[i + 1] = v;
    cursor[i] = v - deg[i];
  }
}

__global__ void scatter_edges(const int* __restrict__ ei, const float* __restrict__ ea,
                              int* __restrict__ cursor, float4* __restrict__ csr)
{
  int e = blockIdx.x * 256 + threadIdx.x;
  if (e >= EE) return;
  int s = ei[e];
  int d = ei[EE + e];
  float e0 = ea[(size_t)e * 3 + 0];
  float e1 = ea[(size_t)e * 3 + 1];
  float e2 = ea[(size_t)e * 3 + 2];
  int pos = atomicAdd(&cursor[d], 1);
  csr[pos] = make_float4(__int_as_float(s), e0, e1, e2);
}

// ---------------------------------------------------------------------------
// GATv2 gather: wave per dst node; lanes 0-31 head0 / 32-63 head1, float2
// channels per lane. Real edges from CSR (attrs inline); self-loop (attr =
// running mean) folded in at the end.
// ---------------------------------------------------------------------------
template <bool FINAL>
__global__ __launch_bounds__(256) void gat_gather(
    const float* __restrict__ xlr, const int* __restrict__ row_off,
    const float4* __restrict__ csr,
    const float* __restrict__ we, const float* __restrict__ att,
    const float* __restrict__ bo, const float* __restrict__ pw,
    float* __restrict__ out)
{
  __shared__ float we_s[384];
  __shared__ float att_s[128];
  __shared__ float bo_s[64], pw_s[64];
  int tid = threadIdx.x;
  for (int i = tid; i < 384; i += 256) we_s[i] = we[i];
  if (tid < 128) att_s[tid] = att[tid];
  if (tid < 64) { bo_s[tid] = bo[tid]; pw_s[tid] = FINAL ? pw[tid] : 0.f; }
  __syncthreads();

  int wv = tid >> 6, lane = tid & 63;
  int n = blockIdx.x * 4 + wv;
  if (n >= NN) return;

  const int half = lane >> 5;
  const int hl = lane & 31;
  const int cb = half * 64 + hl * 2;

  float2 xr = *reinterpret_cast<const float2*>(&xlr[(size_t)n * 256 + 128 + cb]);
  float w0a = we_s[cb],       w0b = we_s[cb + 1];
  float w1a = we_s[128 + cb], w1b = we_s[128 + cb + 1];
  float w2a = we_s[256 + cb], w2b = we_s[256 + cb + 1];
  float ata = att_s[cb], atb = att_s[cb + 1];

  int ro = row_off[n], re = row_off[n + 1];
  float m = -INFINITY, s = 0.f, a0 = 0.f, a1 = 0.f;
  float se0 = 0.f, se1 = 0.f, se2 = 0.f;   // attr sums (same in all lanes)

  int i = ro;
  for (; i + 1 < re; i += 2) {
    float4 cA = csr[i];
    float4 cB = csr[i + 1];
    int sA = __float_as_int(cA.x);
    int sB = __float_as_int(cB.x);
    float2 xlA = *reinterpret_cast<const float2*>(&xlr[(size_t)sA * 256 + cb]);
    float2 xlB = *reinterpret_cast<const float2*>(&xlr[(size_t)sB * 256 + cb]);
    se0 += cA.y + cB.y; se1 += cA.z + cB.z; se2 += cA.w + cB.w;
    float tA0 = xlA.x + xr.x + cA.y * w0a + cA.z * w1a + cA.w * w2a;
    float tA1 = xlA.y + xr.y + cA.y * w0b + cA.z * w1b + cA.w * w2b;
    float tB0 = xlB.x + xr.x + cB.y * w0a + cB.z * w1a + cB.w * w2a;
    float tB1 = xlB.y + xr.y + cB.y * w0b + cB.z * w1b + cB.w * w2b;
    tA0 = tA0 > 0.f ? tA0 : 0.2f * tA0;
    tA1 = tA1 > 0.f ? tA1 : 0.2f * tA1;
    tB0 = tB0 > 0.f ? tB0 : 0.2f * tB0;
    tB1 = tB1 > 0.f ? tB1 : 0.2f * tB1;
    float vA = tA0 * ata + tA1 * atb;
    float vB = tB0 * ata + tB1 * atb;
#pragma unroll
    for (int off = 16; off; off >>= 1) {
      vA += __shfl_xor(vA, off);
      vB += __shfl_xor(vB, off);
    }
    float nm = fmaxf(m, fmaxf(vA, vB));
    float sc = __expf(m - nm);
    float qA = __expf(vA - nm);
    float qB = __expf(vB - nm);
    s = s * sc + qA + qB;
    a0 = a0 * sc + qA * xlA.x + qB * xlB.x;
    a1 = a1 * sc + qA * xlA.y + qB * xlB.y;
    m = nm;
  }
  if (i < re) {
    float4 cA = csr[i];
    int sA = __float_as_int(cA.x);
    float2 xlA = *reinterpret_cast<const float2*>(&xlr[(size_t)sA * 256 + cb]);
    se0 += cA.y; se1 += cA.z; se2 += cA.w;
    float tA0 = xlA.x + xr.x + cA.y * w0a + cA.z * w1a + cA.w * w2a;
    float tA1 = xlA.y + xr.y + cA.y * w0b + cA.z * w1b + cA.w * w2b;
    tA0 = tA0 > 0.f ? tA0 : 0.2f * tA0;
    tA1 = tA1 > 0.f ? tA1 : 0.2f * tA1;
    float vA = tA0 * ata + tA1 * atb;
#pragma unroll
    for (int off = 16; off; off >>= 1) vA += __shfl_xor(vA, off);
    float nm = fmaxf(m, vA);
    float sc = __expf(m - nm);
    float qA = __expf(vA - nm);
    s = s * sc + qA;
    a0 = a0 * sc + qA * xlA.x;
    a1 = a1 * sc + qA * xlA.y;
    m = nm;
  }

  // self-loop: src = n, attr = mean of in-edge attrs
  {
    float inv = 1.f / fmaxf((float)(re - ro), 1.f);
    float me0 = se0 * inv, me1 = se1 * inv, me2 = se2 * inv;
    float2 xlS = *reinterpret_cast<const float2*>(&xlr[(size_t)n * 256 + cb]);
    float tS0 = xlS.x + xr.x + me0 * w0a + me1 * w1a + me2 * w2a;
    float tS1 = xlS.y + xr.y + me0 * w0b + me1 * w1b + me2 * w2b;
    tS0 = tS0 > 0.f ? tS0 : 0.2f * tS0;
    tS1 = tS1 > 0.f ? tS1 : 0.2f * tS1;
    float vS = tS0 * ata + tS1 * atb;
#pragma unroll
    for (int off = 16; off; off >>= 1) vS += __shfl_xor(vS, off);
    float nm = fmaxf(m, vS);
    float sc = __expf(m - nm);
    float qS = __expf(vS - nm);
    s = s * sc + qS;
    a0 = a0 * sc + qS * xlS.x;
    a1 = a1 * sc + qS * xlS.y;
  }

  float f0 = a0 / s, f1 = a1 / s;
  float g0 = __shfl_xor(f0, 32);
  float g1 = __shfl_xor(f1, 32);
  if (half == 0) {
    float2 r;
    r.x = 0.5f * (f0 + g0) + bo_s[hl * 2];
    r.y = 0.5f * (f1 + g1) + bo_s[hl * 2 + 1];
    if (FINAL) {
      r.x = (r.x >= 0.f) ? r.x : pw_s[hl * 2] * r.x;
      r.y = (r.y >= 0.f) ? r.y : pw_s[hl * 2 + 1] * r.y;
    }
    *reinterpret_cast<float2*>(&out[(size_t)n * 64 + hl * 2]) = r;
  }
}

// ---------------------------------------------------------------------------
extern "C" void kernel_launch(void* const* d_in, const int* in_sizes, int n_in,
                              void* d_out, int out_size, void* d_ws, size_t ws_size,
                              hipStream_t stream)
{
  const float* x     = (const float*)d_in[0];
  const int*   ei    = (const int*)d_in[1];
  const float* eattr = (const float*)d_in[2];
  const float* wl1 = (const float*)d_in[3];
  const float* bl1 = (const float*)d_in[4];
  const float* wr1 = (const float*)d_in[5];
  const float* br1 = (const float*)d_in[6];
  const float* we1 = (const float*)d_in[7];
  const float* att1 = (const float*)d_in[8];
  const float* bo1 = (const float*)d_in[9];
  const float* wl2 = (const float*)d_in[10];
  const float* bl2 = (const float*)d_in[11];
  const float* wr2 = (const float*)d_in[12];
  const float* br2 = (const float*)d_in[13];
  const float* we2 = (const float*)d_in[14];
  const float* att2 = (const float*)d_in[15];
  const float* bo2 = (const float*)d_in[16];
  const float* prelu = (const float*)d_in[17];
  float* out = (float*)d_out;

  float* fws  = (float*)d_ws;
  float* xlr  = fws;                           // N*256 f32
  float* h1   = xlr + (size_t)NN * 256;        // N*64 f32
  float4* csr = (float4*)(h1 + (size_t)NN * 64); // EE float4 (16B aligned)
  int* deg     = (int*)(csr + EE);             // N
  int* row_off = deg + NN;                     // N+1
  int* cursor  = row_off + NN + 1;             // N
  int* bsum    = cursor + NN;                  // NB
  int* boff    = bsum + NB;                    // NB

  // wt1 aliases h1 (dead until gat1 writes h1); wt2 aliases deg/cursor
  // (dead after scatter_edges).
  short* wt1a = (short*)h1;
  short* wt1b = wt1a + (size_t)128 * 1536;
  short* wt2a = (short*)deg;
  short* wt2b = (short*)cursor;

  hipMemsetAsync(deg, 0, (size_t)NN * 4, stream);

  int ebl = (EE + 255) / 256;

  count_deg<<<ebl, 256, 0, stream>>>(ei, deg);
  scan_blocks<<<NB, 256, 0, stream>>>(deg, row_off, bsum);
  scan_tops<<<1, 256, 0, stream>>>(bsum, boff);
  scan_add<<<NB, 256, 0, stream>>>(row_off, boff, deg, cursor);
  scatter_edges<<<ebl, 256, 0, stream>>>(ei, eattr, cursor, csr);

  dim3 ggrid((NN + 127) / 128, 2);

  // layer 1
  build_wt<<<(128 * 512 + 255) / 256, 256, 0, stream>>>(wl1, wt1a, 512);
  build_wt<<<(128 * 512 + 255) / 256, 256, 0, stream>>>(wr1, wt1b, 512);
  gemm_mfma<512, 8><<<ggrid, 256, 0, stream>>>(x, NN, wt1a, bl1, wt1b, br1, xlr);
  gat_gather<false><<<(NN + 3) / 4, 256, 0, stream>>>(
      xlr, row_off, csr, we1, att1, bo1, prelu, h1);

  // layer 2 (wt2 built after scatter consumed cursor/deg)
  build_wt<<<(128 * 64 + 255) / 256, 256, 0, stream>>>(wl2, wt2a, 64);
  build_wt<<<(128 * 64 + 255) / 256, 256, 0, stream>>>(wr2, wt2b, 64);
  gemm_mfma<64, 1><<<ggrid, 256, 0, stream>>>(h1, NN, wt2a, bl2, wt2b, br2, xlr);
  gat_gather<true><<<(NN + 3) / 4, 256, 0, stream>>>(
      xlr, row_off, csr, we2, att2, bo2, prelu, out);
}

// Round 5
// 375.563 us; speedup vs baseline: 2.2726x; 1.2146x over previous
//
#include <hip/hip_runtime.h>
#include <math.h>

#define NN 50000
#define EE 800000
#define NB ((NN + 255) / 256)   // 196 scan blocks

typedef __attribute__((ext_vector_type(8))) short bf16x8;
typedef __attribute__((ext_vector_type(4))) float f32x4;

__device__ __forceinline__ short f2bf(float f) {
  unsigned u = __float_as_uint(f);
  unsigned r = (u + 0x7FFFu + ((u >> 16) & 1u)) >> 16;
  return (short)r;
}
__device__ __forceinline__ float bf2f(short h) {
  return __uint_as_float(((unsigned)(unsigned short)h) << 16);
}

// ---------------------------------------------------------------------------
// Wt builder: w [K][128] f32 -> wt [128][2K] bf16 rows = [hi | lo]
// ---------------------------------------------------------------------------
__global__ void build_wt(const float* __restrict__ w, short* __restrict__ wt, int K)
{
  int idx = blockIdx.x * 256 + threadIdx.x;
  if (idx >= 128 * K) return;
  int k = idx % K;
  int c = idx / K;
  float v = w[(size_t)k * 128 + c];
  short hi = f2bf(v);
  short lo = f2bf(v - bf2f(hi));
  size_t base = (size_t)c * 2 * K;
  wt[base + k] = hi;
  wt[base + K + k] = lo;
}

// ---------------------------------------------------------------------------
// bf16x3 split MFMA GEMM, single-pass over A:
// out[M,256] = A[M,K] @ [W0|W1] + [b0|b1], f32-accurate via
// A_hi*W_hi + A_lo*W_hi + A_hi*W_lo computed per K-chunk from one staging.
// tile 128x128, BK=64, 256 threads (4 waves x 64x64), grid (ceil(M/128), 2)
// ---------------------------------------------------------------------------
template <int K, int KS>   // KS = K/64
__global__ __launch_bounds__(256) void gemm_mfma(
    const float* __restrict__ A, int M,
    const short* __restrict__ Wt0, const float* __restrict__ b0,
    const short* __restrict__ Wt1, const float* __restrict__ b1,
    float* __restrict__ out)
{
  const int bn = blockIdx.y;
  const short* __restrict__ Wt = bn ? Wt1 : Wt0;
  const float* __restrict__ bias = bn ? b1 : b0;
  __shared__ __align__(16) short As_hi[128][64];
  __shared__ __align__(16) short As_lo[128][64];
  __shared__ __align__(16) short Ws_hi[128][64];
  __shared__ __align__(16) short Ws_lo[128][64];
  const int tid = threadIdx.x;
  const int m0 = blockIdx.x * 128;
  const int lane = tid & 63;
  const int wv = tid >> 6;
  const int wr = wv >> 1, wc = wv & 1;
  const int rsel = lane & 15, ksel = lane >> 4, sx = lane & 7;

  f32x4 acc[4][4];
#pragma unroll
  for (int i = 0; i < 4; ++i)
#pragma unroll
    for (int j = 0; j < 4; ++j) acc[i][j] = (f32x4)(0.f);

  for (int t = 0; t < KS; ++t) {
    const int k0 = t * 64;
    // ---- stage A chunk once: split into hi + lo ----
#pragma unroll
    for (int i = 0; i < 4; ++i) {
      int f = tid + i * 256;               // 1024 slots of 8 elems
      int kb = f & 7, m = f >> 3;
      int row = m0 + m;
      float4 v0 = make_float4(0.f, 0.f, 0.f, 0.f), v1 = v0;
      if (row < M) {
        const float* p = A + (size_t)row * K + k0 + kb * 8;
        v0 = *reinterpret_cast<const float4*>(p);
        v1 = *reinterpret_cast<const float4*>(p + 4);
      }
      float xs[8] = {v0.x, v0.y, v0.z, v0.w, v1.x, v1.y, v1.z, v1.w};
      bf16x8 ohi, olo;
#pragma unroll
      for (int j = 0; j < 8; ++j) {
        short h = f2bf(xs[j]);
        ohi[j] = h;
        olo[j] = f2bf(xs[j] - bf2f(h));
      }
      int sl = (kb ^ (m & 7)) * 8;
      *reinterpret_cast<bf16x8*>(&As_hi[m][sl]) = ohi;
      *reinterpret_cast<bf16x8*>(&As_lo[m][sl]) = olo;
    }
    // ---- stage W chunk: hi + lo ----
#pragma unroll
    for (int i = 0; i < 4; ++i) {
      int f = tid + i * 256;
      int kb = f & 7, c = f >> 3;
      const short* pw = &Wt[(size_t)c * (2 * K) + k0 + kb * 8];
      bf16x8 vh = *reinterpret_cast<const bf16x8*>(pw);
      bf16x8 vl = *reinterpret_cast<const bf16x8*>(pw + K);
      int sl = (kb ^ (c & 7)) * 8;
      *reinterpret_cast<bf16x8*>(&Ws_hi[c][sl]) = vh;
      *reinterpret_cast<bf16x8*>(&Ws_lo[c][sl]) = vl;
    }
    __syncthreads();
    // ---- MFMA: 3 products off one staging ----
#pragma unroll
    for (int kk = 0; kk < 2; ++kk) {
      bf16x8 ah[4], al[4], bh[4], bl[4];
#pragma unroll
      for (int mf = 0; mf < 4; ++mf) {
        int r = wr * 64 + mf * 16 + rsel;
        int sl = ((kk * 4 + ksel) ^ sx) * 8;
        ah[mf] = *reinterpret_cast<const bf16x8*>(&As_hi[r][sl]);
        al[mf] = *reinterpret_cast<const bf16x8*>(&As_lo[r][sl]);
      }
#pragma unroll
      for (int cf = 0; cf < 4; ++cf) {
        int r = wc * 64 + cf * 16 + rsel;
        int sl = ((kk * 4 + ksel) ^ sx) * 8;
        bh[cf] = *reinterpret_cast<const bf16x8*>(&Ws_hi[r][sl]);
        bl[cf] = *reinterpret_cast<const bf16x8*>(&Ws_lo[r][sl]);
      }
#pragma unroll
      for (int mf = 0; mf < 4; ++mf)
#pragma unroll
        for (int cf = 0; cf < 4; ++cf) {
          acc[mf][cf] = __builtin_amdgcn_mfma_f32_16x16x32_bf16(
              ah[mf], bh[cf], acc[mf][cf], 0, 0, 0);
          acc[mf][cf] = __builtin_amdgcn_mfma_f32_16x16x32_bf16(
              al[mf], bh[cf], acc[mf][cf], 0, 0, 0);
          acc[mf][cf] = __builtin_amdgcn_mfma_f32_16x16x32_bf16(
              ah[mf], bl[cf], acc[mf][cf], 0, 0, 0);
        }
    }
    __syncthreads();
  }
  // ---- epilogue ----
#pragma unroll
  for (int mf = 0; mf < 4; ++mf) {
#pragma unroll
    for (int j = 0; j < 4; ++j) {
      int row = m0 + wr * 64 + mf * 16 + ksel * 4 + j;
      if (row >= M) continue;
#pragma unroll
      for (int cf = 0; cf < 4; ++cf) {
        int col = wc * 64 + cf * 16 + rsel;
        out[(size_t)row * 256 + bn * 128 + col] = acc[mf][cf][j] + bias[col];
      }
    }
  }
}

// ---------------------------------------------------------------------------
// CSR build: int histogram -> scan -> scatter (entry = {src, e0,e1,e2})
// ---------------------------------------------------------------------------
__global__ void count_deg(const int* __restrict__ ei, int* __restrict__ deg)
{
  int e = blockIdx.x * 256 + threadIdx.x;
  if (e >= EE) return;
  atomicAdd(&deg[ei[EE + e]], 1);
}

__global__ __launch_bounds__(256) void scan_blocks(const int* __restrict__ deg,
                                                   int* __restrict__ row_off,
                                                   int* __restrict__ bsum)
{
  int b = blockIdx.x, tid = threadIdx.x;
  int i = b * 256 + tid;
  int v = (i < NN) ? deg[i] : 0;
  int lane = tid & 63, wv = tid >> 6;
  int x = v;
#pragma unroll
  for (int off = 1; off < 64; off <<= 1) {
    int t = __shfl_up(x, off);
    if (lane >= off) x += t;
  }
  __shared__ int ws[4], wo[4];
  if (lane == 63) ws[wv] = x;
  __syncthreads();
  if (tid == 0) {
    int s = 0;
#pragma unroll
    for (int k = 0; k < 4; ++k) { wo[k] = s; s += ws[k]; }
    bsum[b] = s;
  }
  __syncthreads();
  x += wo[wv];
  if (i < NN) row_off[i + 1] = x;
}

__global__ __launch_bounds__(256) void scan_tops(const int* __restrict__ bsum,
                                                 int* __restrict__ boff)
{
  int tid = threadIdx.x;
  int v = (tid < NB) ? bsum[tid] : 0;
  int lane = tid & 63, wv = tid >> 6;
  int x = v;
#pragma unroll
  for (int off = 1; off < 64; off <<= 1) {
    int t = __shfl_up(x, off);
    if (lane >= off) x += t;
  }
  __shared__ int ws[4], wo[4];
  if (lane == 63) ws[wv] = x;
  __syncthreads();
  if (tid == 0) {
    int s = 0;
#pragma unroll
    for (int k = 0; k < 4; ++k) { wo[k] = s; s += ws[k]; }
  }
  __syncthreads();
  x += wo[wv];
  if (tid < NB) boff[tid] = x - v;   // exclusive
}

// finalize row_off, emit cursor (exclusive start per node)
__global__ void scan_add(int* __restrict__ row_off, const int* __restrict__ boff,
                         const int* __restrict__ deg, int* __restrict__ cursor)
{
  int i = blockIdx.x * 256 + threadIdx.x;
  if (i == 0) row_off[0] = 0;
  if (i < NN) {
    int v = row_off[i + 1] + boff[blockIdx.x];
    row_off[i + 1] = v;
    cursor[i] = v - deg[i];
  }
}

__global__ void scatter_edges(const int* __restrict__ ei, const float* __restrict__ ea,
                              int* __restrict__ cursor, float4* __restrict__ csr)
{
  int e = blockIdx.x * 256 + threadIdx.x;
  if (e >= EE) return;
  int s = ei[e];
  int d = ei[EE + e];
  float e0 = ea[(size_t)e * 3 + 0];
  float e1 = ea[(size_t)e * 3 + 1];
  float e2 = ea[(size_t)e * 3 + 2];
  int pos = atomicAdd(&cursor[d], 1);
  csr[pos] = make_float4(__int_as_float(s), e0, e1, e2);
}

// ---------------------------------------------------------------------------
// GATv2 gather: wave per dst node; lanes 0-31 head0 / 32-63 head1, float2
// channels per lane. Real edges from CSR (attrs inline); self-loop (attr =
// running mean) folded in at the end.
// ---------------------------------------------------------------------------
template <bool FINAL>
__global__ __launch_bounds__(256) void gat_gather(
    const float* __restrict__ xlr, const int* __restrict__ row_off,
    const float4* __restrict__ csr,
    const float* __restrict__ we, const float* __restrict__ att,
    const float* __restrict__ bo, const float* __restrict__ pw,
    float* __restrict__ out)
{
  __shared__ float we_s[384];
  __shared__ float att_s[128];
  __shared__ float bo_s[64], pw_s[64];
  int tid = threadIdx.x;
  for (int i = tid; i < 384; i += 256) we_s[i] = we[i];
  if (tid < 128) att_s[tid] = att[tid];
  if (tid < 64) { bo_s[tid] = bo[tid]; pw_s[tid] = FINAL ? pw[tid] : 0.f; }
  __syncthreads();

  int wv = tid >> 6, lane = tid & 63;
  int n = blockIdx.x * 4 + wv;
  if (n >= NN) return;

  const int half = lane >> 5;
  const int hl = lane & 31;
  const int cb = half * 64 + hl * 2;

  float2 xr = *reinterpret_cast<const float2*>(&xlr[(size_t)n * 256 + 128 + cb]);
  float w0a = we_s[cb],       w0b = we_s[cb + 1];
  float w1a = we_s[128 + cb], w1b = we_s[128 + cb + 1];
  float w2a = we_s[256 + cb], w2b = we_s[256 + cb + 1];
  float ata = att_s[cb], atb = att_s[cb + 1];

  int ro = row_off[n], re = row_off[n + 1];
  float m = -INFINITY, s = 0.f, a0 = 0.f, a1 = 0.f;
  float se0 = 0.f, se1 = 0.f, se2 = 0.f;

  int i = ro;
  for (; i + 1 < re; i += 2) {
    float4 cA = csr[i];
    float4 cB = csr[i + 1];
    int sA = __float_as_int(cA.x);
    int sB = __float_as_int(cB.x);
    float2 xlA = *reinterpret_cast<const float2*>(&xlr[(size_t)sA * 256 + cb]);
    float2 xlB = *reinterpret_cast<const float2*>(&xlr[(size_t)sB * 256 + cb]);
    se0 += cA.y + cB.y; se1 += cA.z + cB.z; se2 += cA.w + cB.w;
    float tA0 = xlA.x + xr.x + cA.y * w0a + cA.z * w1a + cA.w * w2a;
    float tA1 = xlA.y + xr.y + cA.y * w0b + cA.z * w1b + cA.w * w2b;
    float tB0 = xlB.x + xr.x + cB.y * w0a + cB.z * w1a + cB.w * w2a;
    float tB1 = xlB.y + xr.y + cB.y * w0b + cB.z * w1b + cB.w * w2b;
    tA0 = tA0 > 0.f ? tA0 : 0.2f * tA0;
    tA1 = tA1 > 0.f ? tA1 : 0.2f * tA1;
    tB0 = tB0 > 0.f ? tB0 : 0.2f * tB0;
    tB1 = tB1 > 0.f ? tB1 : 0.2f * tB1;
    float vA = tA0 * ata + tA1 * atb;
    float vB = tB0 * ata + tB1 * atb;
#pragma unroll
    for (int off = 16; off; off >>= 1) {
      vA += __shfl_xor(vA, off);
      vB += __shfl_xor(vB, off);
    }
    float nm = fmaxf(m, fmaxf(vA, vB));
    float sc = __expf(m - nm);
    float qA = __expf(vA - nm);
    float qB = __expf(vB - nm);
    s = s * sc + qA + qB;
    a0 = a0 * sc + qA * xlA.x + qB * xlB.x;
    a1 = a1 * sc + qA * xlA.y + qB * xlB.y;
    m = nm;
  }
  if (i < re) {
    float4 cA = csr[i];
    int sA = __float_as_int(cA.x);
    float2 xlA = *reinterpret_cast<const float2*>(&xlr[(size_t)sA * 256 + cb]);
    se0 += cA.y; se1 += cA.z; se2 += cA.w;
    float tA0 = xlA.x + xr.x + cA.y * w0a + cA.z * w1a + cA.w * w2a;
    float tA1 = xlA.y + xr.y + cA.y * w0b + cA.z * w1b + cA.w * w2b;
    tA0 = tA0 > 0.f ? tA0 : 0.2f * tA0;
    tA1 = tA1 > 0.f ? tA1 : 0.2f * tA1;
    float vA = tA0 * ata + tA1 * atb;
#pragma unroll
    for (int off = 16; off; off >>= 1) vA += __shfl_xor(vA, off);
    float nm = fmaxf(m, vA);
    float sc = __expf(m - nm);
    float qA = __expf(vA - nm);
    s = s * sc + qA;
    a0 = a0 * sc + qA * xlA.x;
    a1 = a1 * sc + qA * xlA.y;
    m = nm;
  }

  // self-loop: src = n, attr = mean of in-edge attrs
  {
    float inv = 1.f / fmaxf((float)(re - ro), 1.f);
    float me0 = se0 * inv, me1 = se1 * inv, me2 = se2 * inv;
    float2 xlS = *reinterpret_cast<const float2*>(&xlr[(size_t)n * 256 + cb]);
    float tS0 = xlS.x + xr.x + me0 * w0a + me1 * w1a + me2 * w2a;
    float tS1 = xlS.y + xr.y + me0 * w0b + me1 * w1b + me2 * w2b;
    tS0 = tS0 > 0.f ? tS0 : 0.2f * tS0;
    tS1 = tS1 > 0.f ? tS1 : 0.2f * tS1;
    float vS = tS0 * ata + tS1 * atb;
#pragma unroll
    for (int off = 16; off; off >>= 1) vS += __shfl_xor(vS, off);
    float nm = fmaxf(m, vS);
    float sc = __expf(m - nm);
    float qS = __expf(vS - nm);
    s = s * sc + qS;
    a0 = a0 * sc + qS * xlS.x;
    a1 = a1 * sc + qS * xlS.y;
  }

  float f0 = a0 / s, f1 = a1 / s;
  float g0 = __shfl_xor(f0, 32);
  float g1 = __shfl_xor(f1, 32);
  if (half == 0) {
    float2 r;
    r.x = 0.5f * (f0 + g0) + bo_s[hl * 2];
    r.y = 0.5f * (f1 + g1) + bo_s[hl * 2 + 1];
    if (FINAL) {
      r.x = (r.x >= 0.f) ? r.x : pw_s[hl * 2] * r.x;
      r.y = (r.y >= 0.f) ? r.y : pw_s[hl * 2 + 1] * r.y;
    }
    *reinterpret_cast<float2*>(&out[(size_t)n * 64 + hl * 2]) = r;
  }
}

// ---------------------------------------------------------------------------
extern "C" void kernel_launch(void* const* d_in, const int* in_sizes, int n_in,
                              void* d_out, int out_size, void* d_ws, size_t ws_size,
                              hipStream_t stream)
{
  const float* x     = (const float*)d_in[0];
  const int*   ei    = (const int*)d_in[1];
  const float* eattr = (const float*)d_in[2];
  const float* wl1 = (const float*)d_in[3];
  const float* bl1 = (const float*)d_in[4];
  const float* wr1 = (const float*)d_in[5];
  const float* br1 = (const float*)d_in[6];
  const float* we1 = (const float*)d_in[7];
  const float* att1 = (const float*)d_in[8];
  const float* bo1 = (const float*)d_in[9];
  const float* wl2 = (const float*)d_in[10];
  const float* bl2 = (const float*)d_in[11];
  const float* wr2 = (const float*)d_in[12];
  const float* br2 = (const float*)d_in[13];
  const float* we2 = (const float*)d_in[14];
  const float* att2 = (const float*)d_in[15];
  const float* bo2 = (const float*)d_in[16];
  const float* prelu = (const float*)d_in[17];
  float* out = (float*)d_out;

  float* fws  = (float*)d_ws;
  float* xlr  = fws;                             // N*256 f32
  float* h1   = xlr + (size_t)NN * 256;          // N*64 f32
  float4* csr = (float4*)(h1 + (size_t)NN * 64); // EE float4
  int* deg     = (int*)(csr + EE);               // N
  int* row_off = deg + NN;                       // N+1
  int* cursor  = row_off + NN + 1;               // N
  int* bsum    = cursor + NN;                    // NB
  int* boff    = bsum + NB;                      // NB

  // wt1 (2 x 128x1024 bf16 = 512 KB) aliases h1 (12.8 MB, dead until gat1);
  // wt2 (2 x 128x128 bf16 = 64 KB) aliases deg/cursor (dead after scatter).
  short* wt1a = (short*)h1;
  short* wt1b = wt1a + (size_t)128 * 1024;
  short* wt2a = (short*)deg;
  short* wt2b = (short*)cursor;

  hipMemsetAsync(deg, 0, (size_t)NN * 4, stream);

  int ebl = (EE + 255) / 256;

  count_deg<<<ebl, 256, 0, stream>>>(ei, deg);
  scan_blocks<<<NB, 256, 0, stream>>>(deg, row_off, bsum);
  scan_tops<<<1, 256, 0, stream>>>(bsum, boff);
  scan_add<<<NB, 256, 0, stream>>>(row_off, boff, deg, cursor);
  scatter_edges<<<ebl, 256, 0, stream>>>(ei, eattr, cursor, csr);

  dim3 ggrid((NN + 127) / 128, 2);

  // layer 1
  build_wt<<<(128 * 512 + 255) / 256, 256, 0, stream>>>(wl1, wt1a, 512);
  build_wt<<<(128 * 512 + 255) / 256, 256, 0, stream>>>(wr1, wt1b, 512);
  gemm_mfma<512, 8><<<ggrid, 256, 0, stream>>>(x, NN, wt1a, bl1, wt1b, br1, xlr);
  gat_gather<false><<<(NN + 3) / 4, 256, 0, stream>>>(
      xlr, row_off, csr, we1, att1, bo1, prelu, h1);

  // layer 2 (wt2 built after scatter consumed cursor/deg)
  build_wt<<<(128 * 64 + 255) / 256, 256, 0, stream>>>(wl2, wt2a, 64);
  build_wt<<<(128 * 64 + 255) / 256, 256, 0, stream>>>(wr2, wt2b, 64);
  gemm_mfma<64, 1><<<ggrid, 256, 0, stream>>>(h1, NN, wt2a, bl2, wt2b, br2, xlr);
  gat_gather<true><<<(NN + 3) / 4, 256, 0, stream>>>(
      xlr, row_off, csr, we2, att2, bo2, prelu, out);
}

// Round 6
// 348.247 us; speedup vs baseline: 2.4509x; 1.0784x over previous
//
#include <hip/hip_runtime.h>
#include <math.h>

#define NN 50000
#define EE 800000
#define NB ((NN + 255) / 256)   // 196 scan blocks

typedef __attribute__((ext_vector_type(8))) short bf16x8;
typedef __attribute__((ext_vector_type(4))) float f32x4;

__device__ __forceinline__ short f2bf(float f) {
  unsigned u = __float_as_uint(f);
  unsigned r = (u + 0x7FFFu + ((u >> 16) & 1u)) >> 16;
  return (short)r;
}
__device__ __forceinline__ float bf2f(short h) {
  return __uint_as_float(((unsigned)(unsigned short)h) << 16);
}

// ---------------------------------------------------------------------------
// Wt builder: w [K][128] f32 -> wt [128][2K] bf16 rows = [hi | lo]
// ---------------------------------------------------------------------------
__global__ void build_wt(const float* __restrict__ w, short* __restrict__ wt, int K)
{
  int idx = blockIdx.x * 256 + threadIdx.x;
  if (idx >= 128 * K) return;
  int k = idx % K;
  int c = idx / K;
  float v = w[(size_t)k * 128 + c];
  short hi = f2bf(v);
  short lo = f2bf(v - bf2f(hi));
  size_t base = (size_t)c * 2 * K;
  wt[base + k] = hi;
  wt[base + K + k] = lo;
}

// ---------------------------------------------------------------------------
// bf16x3 split MFMA GEMM, single-pass over A (unchanged from round 5)
// ---------------------------------------------------------------------------
template <int K, int KS>   // KS = K/64
__global__ __launch_bounds__(256) void gemm_mfma(
    const float* __restrict__ A, int M,
    const short* __restrict__ Wt0, const float* __restrict__ b0,
    const short* __restrict__ Wt1, const float* __restrict__ b1,
    float* __restrict__ out)
{
  const int bn = blockIdx.y;
  const short* __restrict__ Wt = bn ? Wt1 : Wt0;
  const float* __restrict__ bias = bn ? b1 : b0;
  __shared__ __align__(16) short As_hi[128][64];
  __shared__ __align__(16) short As_lo[128][64];
  __shared__ __align__(16) short Ws_hi[128][64];
  __shared__ __align__(16) short Ws_lo[128][64];
  const int tid = threadIdx.x;
  const int m0 = blockIdx.x * 128;
  const int lane = tid & 63;
  const int wv = tid >> 6;
  const int wr = wv >> 1, wc = wv & 1;
  const int rsel = lane & 15, ksel = lane >> 4, sx = lane & 7;

  f32x4 acc[4][4];
#pragma unroll
  for (int i = 0; i < 4; ++i)
#pragma unroll
    for (int j = 0; j < 4; ++j) acc[i][j] = (f32x4)(0.f);

  for (int t = 0; t < KS; ++t) {
    const int k0 = t * 64;
#pragma unroll
    for (int i = 0; i < 4; ++i) {
      int f = tid + i * 256;
      int kb = f & 7, m = f >> 3;
      int row = m0 + m;
      float4 v0 = make_float4(0.f, 0.f, 0.f, 0.f), v1 = v0;
      if (row < M) {
        const float* p = A + (size_t)row * K + k0 + kb * 8;
        v0 = *reinterpret_cast<const float4*>(p);
        v1 = *reinterpret_cast<const float4*>(p + 4);
      }
      float xs[8] = {v0.x, v0.y, v0.z, v0.w, v1.x, v1.y, v1.z, v1.w};
      bf16x8 ohi, olo;
#pragma unroll
      for (int j = 0; j < 8; ++j) {
        short h = f2bf(xs[j]);
        ohi[j] = h;
        olo[j] = f2bf(xs[j] - bf2f(h));
      }
      int sl = (kb ^ (m & 7)) * 8;
      *reinterpret_cast<bf16x8*>(&As_hi[m][sl]) = ohi;
      *reinterpret_cast<bf16x8*>(&As_lo[m][sl]) = olo;
    }
#pragma unroll
    for (int i = 0; i < 4; ++i) {
      int f = tid + i * 256;
      int kb = f & 7, c = f >> 3;
      const short* pw = &Wt[(size_t)c * (2 * K) + k0 + kb * 8];
      bf16x8 vh = *reinterpret_cast<const bf16x8*>(pw);
      bf16x8 vl = *reinterpret_cast<const bf16x8*>(pw + K);
      int sl = (kb ^ (c & 7)) * 8;
      *reinterpret_cast<bf16x8*>(&Ws_hi[c][sl]) = vh;
      *reinterpret_cast<bf16x8*>(&Ws_lo[c][sl]) = vl;
    }
    __syncthreads();
#pragma unroll
    for (int kk = 0; kk < 2; ++kk) {
      bf16x8 ah[4], al[4], bh[4], bl[4];
#pragma unroll
      for (int mf = 0; mf < 4; ++mf) {
        int r = wr * 64 + mf * 16 + rsel;
        int sl = ((kk * 4 + ksel) ^ sx) * 8;
        ah[mf] = *reinterpret_cast<const bf16x8*>(&As_hi[r][sl]);
        al[mf] = *reinterpret_cast<const bf16x8*>(&As_lo[r][sl]);
      }
#pragma unroll
      for (int cf = 0; cf < 4; ++cf) {
        int r = wc * 64 + cf * 16 + rsel;
        int sl = ((kk * 4 + ksel) ^ sx) * 8;
        bh[cf] = *reinterpret_cast<const bf16x8*>(&Ws_hi[r][sl]);
        bl[cf] = *reinterpret_cast<const bf16x8*>(&Ws_lo[r][sl]);
      }
#pragma unroll
      for (int mf = 0; mf < 4; ++mf)
#pragma unroll
        for (int cf = 0; cf < 4; ++cf) {
          acc[mf][cf] = __builtin_amdgcn_mfma_f32_16x16x32_bf16(
              ah[mf], bh[cf], acc[mf][cf], 0, 0, 0);
          acc[mf][cf] = __builtin_amdgcn_mfma_f32_16x16x32_bf16(
              al[mf], bh[cf], acc[mf][cf], 0, 0, 0);
          acc[mf][cf] = __builtin_amdgcn_mfma_f32_16x16x32_bf16(
              ah[mf], bl[cf], acc[mf][cf], 0, 0, 0);
        }
    }
    __syncthreads();
  }
#pragma unroll
  for (int mf = 0; mf < 4; ++mf) {
#pragma unroll
    for (int j = 0; j < 4; ++j) {
      int row = m0 + wr * 64 + mf * 16 + ksel * 4 + j;
      if (row >= M) continue;
#pragma unroll
      for (int cf = 0; cf < 4; ++cf) {
        int col = wc * 64 + cf * 16 + rsel;
        out[(size_t)row * 256 + bn * 128 + col] = acc[mf][cf][j] + bias[col];
      }
    }
  }
}

// ---------------------------------------------------------------------------
// CSR build: int histogram -> scan -> scatter (entry = {src, e0,e1,e2})
// ---------------------------------------------------------------------------
__global__ void count_deg(const int* __restrict__ ei, int* __restrict__ deg)
{
  int e = blockIdx.x * 256 + threadIdx.x;
  if (e >= EE) return;
  atomicAdd(&deg[ei[EE + e]], 1);
}

__global__ __launch_bounds__(256) void scan_blocks(const int* __restrict__ deg,
                                                   int* __restrict__ row_off,
                                                   int* __restrict__ bsum)
{
  int b = blockIdx.x, tid = threadIdx.x;
  int i = b * 256 + tid;
  int v = (i < NN) ? deg[i] : 0;
  int lane = tid & 63, wv = tid >> 6;
  int x = v;
#pragma unroll
  for (int off = 1; off < 64; off <<= 1) {
    int t = __shfl_up(x, off);
    if (lane >= off) x += t;
  }
  __shared__ int ws[4], wo[4];
  if (lane == 63) ws[wv] = x;
  __syncthreads();
  if (tid == 0) {
    int s = 0;
#pragma unroll
    for (int k = 0; k < 4; ++k) { wo[k] = s; s += ws[k]; }
    bsum[b] = s;
  }
  __syncthreads();
  x += wo[wv];
  if (i < NN) row_off[i + 1] = x;
}

__global__ __launch_bounds__(256) void scan_tops(const int* __restrict__ bsum,
                                                 int* __restrict__ boff)
{
  int tid = threadIdx.x;
  int v = (tid < NB) ? bsum[tid] : 0;
  int lane = tid & 63, wv = tid >> 6;
  int x = v;
#pragma unroll
  for (int off = 1; off < 64; off <<= 1) {
    int t = __shfl_up(x, off);
    if (lane >= off) x += t;
  }
  __shared__ int ws[4], wo[4];
  if (lane == 63) ws[wv] = x;
  __syncthreads();
  if (tid == 0) {
    int s = 0;
#pragma unroll
    for (int k = 0; k < 4; ++k) { wo[k] = s; s += ws[k]; }
  }
  __syncthreads();
  x += wo[wv];
  if (tid < NB) boff[tid] = x - v;   // exclusive
}

__global__ void scan_add(int* __restrict__ row_off, const int* __restrict__ boff,
                         const int* __restrict__ deg, int* __restrict__ cursor)
{
  int i = blockIdx.x * 256 + threadIdx.x;
  if (i == 0) row_off[0] = 0;
  if (i < NN) {
    int v = row_off[i + 1] + boff[blockIdx.x];
    row_off[i + 1] = v;
    cursor[i] = v - deg[i];
  }
}

__global__ void scatter_edges(const int* __restrict__ ei, const float* __restrict__ ea,
                              int* __restrict__ cursor, float4* __restrict__ csr)
{
  int e = blockIdx.x * 256 + threadIdx.x;
  if (e >= EE) return;
  int s = ei[e];
  int d = ei[EE + e];
  float e0 = ea[(size_t)e * 3 + 0];
  float e1 = ea[(size_t)e * 3 + 1];
  float e2 = ea[(size_t)e * 3 + 2];
  int pos = atomicAdd(&cursor[d], 1);
  csr[pos] = make_float4(__int_as_float(s), e0, e1, e2);
}

// ---------------------------------------------------------------------------
// GATv2 gather v3: wave per dst node, TWO 32-lane edge-groups per wave.
// Within a group: lanes 0-15 = head0, 16-31 = head1; each lane owns a
// float4 channel quad. Score reduce = 4 shfl levels (8..1) per edge pair.
// Groups process disjoint halves of the edge list; states merge via xor-32.
// Self-loop (attr = running mean) folded in at the end.
// ---------------------------------------------------------------------------
__device__ __forceinline__ float edge_score(f32x4 xl, f32x4 xr, float e0, float e1,
                                            float e2, f32x4 w0, f32x4 w1, f32x4 w2,
                                            f32x4 at)
{
  f32x4 z = xl + xr;
  z = __builtin_elementwise_fma((f32x4)(e0), w0, z);
  z = __builtin_elementwise_fma((f32x4)(e1), w1, z);
  z = __builtin_elementwise_fma((f32x4)(e2), w2, z);
  f32x4 t = __builtin_elementwise_max(z, 0.2f * z);
  f32x4 p = t * at;
  return (p.x + p.y) + (p.z + p.w);
}

template <bool FINAL>
__global__ __launch_bounds__(256) void gat_gather(
    const float* __restrict__ xlr, const int* __restrict__ row_off,
    const float4* __restrict__ csr,
    const float* __restrict__ we, const float* __restrict__ att,
    const float* __restrict__ bo, const float* __restrict__ pw,
    float* __restrict__ out)
{
  __shared__ __align__(16) float we_s[384];
  __shared__ __align__(16) float att_s[128];
  __shared__ __align__(16) float bo_s[64], pw_s[64];
  int tid = threadIdx.x;
  for (int i = tid; i < 384; i += 256) we_s[i] = we[i];
  if (tid < 128) att_s[tid] = att[tid];
  if (tid < 64) { bo_s[tid] = bo[tid]; pw_s[tid] = FINAL ? pw[tid] : 0.f; }
  __syncthreads();

  int wv = tid >> 6, lane = tid & 63;
  int n = blockIdx.x * 4 + wv;   // NN % 4 == 0

  const int g   = lane >> 5;                           // edge group
  const int sub = lane & 31;
  const int qb  = (sub >> 4) * 64 + (sub & 15) * 4;    // channel quad base

  f32x4 xr = *reinterpret_cast<const f32x4*>(&xlr[(size_t)n * 256 + 128 + qb]);
  f32x4 w0 = *reinterpret_cast<const f32x4*>(&we_s[qb]);
  f32x4 w1 = *reinterpret_cast<const f32x4*>(&we_s[128 + qb]);
  f32x4 w2 = *reinterpret_cast<const f32x4*>(&we_s[256 + qb]);
  f32x4 at = *reinterpret_cast<const f32x4*>(&att_s[qb]);

  int ro = row_off[n], re = row_off[n + 1];
  int len = re - ro;
  int h0 = (len + 1) >> 1;
  int gs = ro + (g ? h0 : 0);
  int ge = g ? re : ro + h0;

  float m = -INFINITY, s = 0.f;
  f32x4 a = (f32x4)(0.f);
  float se0 = 0.f, se1 = 0.f, se2 = 0.f;

  int i = gs;
  for (; i + 1 < ge; i += 2) {
    float4 cA = csr[i];
    float4 cB = csr[i + 1];
    int sA = __float_as_int(cA.x);
    int sB = __float_as_int(cB.x);
    f32x4 xlA = *reinterpret_cast<const f32x4*>(&xlr[(size_t)sA * 256 + qb]);
    f32x4 xlB = *reinterpret_cast<const f32x4*>(&xlr[(size_t)sB * 256 + qb]);
    float vA = edge_score(xlA, xr, cA.y, cA.z, cA.w, w0, w1, w2, at);
    float vB = edge_score(xlB, xr, cB.y, cB.z, cB.w, w0, w1, w2, at);
#pragma unroll
    for (int off = 8; off; off >>= 1) {
      vA += __shfl_xor(vA, off);
      vB += __shfl_xor(vB, off);
    }
    float nm = fmaxf(m, fmaxf(vA, vB));
    float sc = __expf(m - nm);
    float qA = __expf(vA - nm);
    float qB = __expf(vB - nm);
    s = s * sc + qA + qB;
    a = a * sc + (f32x4)(qA) * xlA + (f32x4)(qB) * xlB;
    m = nm;
    se0 += cA.y + cB.y; se1 += cA.z + cB.z; se2 += cA.w + cB.w;
  }
  if (i < ge) {
    float4 cA = csr[i];
    int sA = __float_as_int(cA.x);
    f32x4 xlA = *reinterpret_cast<const f32x4*>(&xlr[(size_t)sA * 256 + qb]);
    float vA = edge_score(xlA, xr, cA.y, cA.z, cA.w, w0, w1, w2, at);
#pragma unroll
    for (int off = 8; off; off >>= 1) vA += __shfl_xor(vA, off);
    float nm = fmaxf(m, vA);
    float sc = __expf(m - nm);
    float qA = __expf(vA - nm);
    s = s * sc + qA;
    a = a * sc + (f32x4)(qA) * xlA;
    m = nm;
    se0 += cA.y; se1 += cA.z; se2 += cA.w;
  }

  // ---- merge the two edge-groups (lane l <-> l+32 hold same head/quad) ----
  {
    float m2 = __shfl_xor(m, 32);
    float s2 = __shfl_xor(s, 32);
    f32x4 a2;
    a2.x = __shfl_xor(a.x, 32);
    a2.y = __shfl_xor(a.y, 32);
    a2.z = __shfl_xor(a.z, 32);
    a2.w = __shfl_xor(a.w, 32);
    float nm = fmaxf(m, m2);
    nm = (nm == -INFINITY) ? 0.f : nm;   // both-empty guard (no NaN)
    float c1 = __expf(m - nm);
    float c2 = __expf(m2 - nm);
    s = s * c1 + s2 * c2;
    a = a * (f32x4)(c1) + a2 * (f32x4)(c2);
    m = nm;
    se0 += __shfl_xor(se0, 32);
    se1 += __shfl_xor(se1, 32);
    se2 += __shfl_xor(se2, 32);
  }

  // ---- self-loop: src = n, attr = mean of in-edge attrs ----
  {
    float inv = 1.f / fmaxf((float)len, 1.f);
    float me0 = se0 * inv, me1 = se1 * inv, me2 = se2 * inv;
    f32x4 xlS = *reinterpret_cast<const f32x4*>(&xlr[(size_t)n * 256 + qb]);
    float vS = edge_score(xlS, xr, me0, me1, me2, w0, w1, w2, at);
#pragma unroll
    for (int off = 8; off; off >>= 1) vS += __shfl_xor(vS, off);
    float nm = fmaxf(m, vS);
    float sc = __expf(m - nm);
    float qS = __expf(vS - nm);
    s = s * sc + qS;
    a = a * sc + (f32x4)(qS) * xlS;
  }

  // ---- head mean + bias (+PReLU), write by lanes 0-15 ----
  f32x4 f = a * (f32x4)(1.f / s);
  f32x4 gxt;
  gxt.x = __shfl_xor(f.x, 16);
  gxt.y = __shfl_xor(f.y, 16);
  gxt.z = __shfl_xor(f.z, 16);
  gxt.w = __shfl_xor(f.w, 16);
  if (lane < 16) {
    int col = (sub & 15) * 4;
    f32x4 b4 = *reinterpret_cast<const f32x4*>(&bo_s[col]);
    f32x4 r = 0.5f * (f + gxt) + b4;
    if (FINAL) {
      f32x4 p4 = *reinterpret_cast<const f32x4*>(&pw_s[col]);
      r.x = (r.x >= 0.f) ? r.x : p4.x * r.x;
      r.y = (r.y >= 0.f) ? r.y : p4.y * r.y;
      r.z = (r.z >= 0.f) ? r.z : p4.z * r.z;
      r.w = (r.w >= 0.f) ? r.w : p4.w * r.w;
    }
    *reinterpret_cast<f32x4*>(&out[(size_t)n * 64 + col]) = r;
  }
}

// ---------------------------------------------------------------------------
extern "C" void kernel_launch(void* const* d_in, const int* in_sizes, int n_in,
                              void* d_out, int out_size, void* d_ws, size_t ws_size,
                              hipStream_t stream)
{
  const float* x     = (const float*)d_in[0];
  const int*   ei    = (const int*)d_in[1];
  const float* eattr = (const float*)d_in[2];
  const float* wl1 = (const float*)d_in[3];
  const float* bl1 = (const float*)d_in[4];
  const float* wr1 = (const float*)d_in[5];
  const float* br1 = (const float*)d_in[6];
  const float* we1 = (const float*)d_in[7];
  const float* att1 = (const float*)d_in[8];
  const float* bo1 = (const float*)d_in[9];
  const float* wl2 = (const float*)d_in[10];
  const float* bl2 = (const float*)d_in[11];
  const float* wr2 = (const float*)d_in[12];
  const float* br2 = (const float*)d_in[13];
  const float* we2 = (const float*)d_in[14];
  const float* att2 = (const float*)d_in[15];
  const float* bo2 = (const float*)d_in[16];
  const float* prelu = (const float*)d_in[17];
  float* out = (float*)d_out;

  float* fws  = (float*)d_ws;
  float* xlr  = fws;                             // N*256 f32
  float* h1   = xlr + (size_t)NN * 256;          // N*64 f32
  float4* csr = (float4*)(h1 + (size_t)NN * 64); // EE float4
  int* deg     = (int*)(csr + EE);               // N
  int* row_off = deg + NN;                       // N+1
  int* cursor  = row_off + NN + 1;               // N
  int* bsum    = cursor + NN;                    // NB
  int* boff    = bsum + NB;                      // NB

  // wt1 (2 x 128x1024 bf16 = 512 KB) aliases h1 (12.8 MB, dead until gat1);
  // wt2 (2 x 128x128 bf16 = 64 KB) aliases deg/cursor (dead after scatter).
  short* wt1a = (short*)h1;
  short* wt1b = wt1a + (size_t)128 * 1024;
  short* wt2a = (short*)deg;
  short* wt2b = (short*)cursor;

  hipMemsetAsync(deg, 0, (size_t)NN * 4, stream);

  int ebl = (EE + 255) / 256;

  count_deg<<<ebl, 256, 0, stream>>>(ei, deg);
  scan_blocks<<<NB, 256, 0, stream>>>(deg, row_off, bsum);
  scan_tops<<<1, 256, 0, stream>>>(bsum, boff);
  scan_add<<<NB, 256, 0, stream>>>(row_off, boff, deg, cursor);
  scatter_edges<<<ebl, 256, 0, stream>>>(ei, eattr, cursor, csr);

  dim3 ggrid((NN + 127) / 128, 2);

  // layer 1
  build_wt<<<(128 * 512 + 255) / 256, 256, 0, stream>>>(wl1, wt1a, 512);
  build_wt<<<(128 * 512 + 255) / 256, 256, 0, stream>>>(wr1, wt1b, 512);
  gemm_mfma<512, 8><<<ggrid, 256, 0, stream>>>(x, NN, wt1a, bl1, wt1b, br1, xlr);
  gat_gather<false><<<(NN + 3) / 4, 256, 0, stream>>>(
      xlr, row_off, csr, we1, att1, bo1, prelu, h1);

  // layer 2 (wt2 built after scatter consumed cursor/deg)
  build_wt<<<(128 * 64 + 255) / 256, 256, 0, stream>>>(wl2, wt2a, 64);
  build_wt<<<(128 * 64 + 255) / 256, 256, 0, stream>>>(wr2, wt2b, 64);
  gemm_mfma<64, 1><<<ggrid, 256, 0, stream>>>(h1, NN, wt2a, bl2, wt2b, br2, xlr);
  gat_gather<true><<<(NN + 3) / 4, 256, 0, stream>>>(
      xlr, row_off, csr, we2, att2, bo2, prelu, out);
}